// Round 7
// baseline (1533.497 us; speedup 1.0000x reference)
//
#include <hip/hip_runtime.h>
#include <hip/hip_fp16.h>
#include <stdint.h>

typedef unsigned short u16;
typedef unsigned char u8;
typedef unsigned int u32;
typedef __attribute__((ext_vector_type(8))) short short8;
typedef __attribute__((ext_vector_type(4))) float f32x4;

#define NSTEP 26
#define NB 512
#define NT 128
#define NH 256
#define NCLS 100

#define SP 32.0f     // proj_H int8 scale
#define SH 24.0f     // batch_H int8 scale
#define SW 2000.0f   // W_h2h int8 scale
#define S8 127.0f    // h int8 scale

#if defined(__has_builtin)
#if __has_builtin(__builtin_amdgcn_sdot4)
#define HAS_SDOT4 1
#endif
#endif

__device__ __forceinline__ u16 f2bf(float f) {
    unsigned u = __float_as_uint(f);
    return (u16)((u + 0x7FFFu + ((u >> 16) & 1u)) >> 16);
}
__device__ __forceinline__ int q8i(float x, float s) {
    float v = fminf(fmaxf(x * s, -127.f), 127.f);
    return __float2int_rn(v);
}
__device__ __forceinline__ float fast_tanh(float x) {
    float e = __expf(2.f * x);
    return 1.f - 2.f / (e + 1.f);
}
__device__ __forceinline__ float fast_sig(float x) { return 1.f / (1.f + __expf(-x)); }
__device__ __forceinline__ void async_g2l(const void* g, void* l) {
    __builtin_amdgcn_global_load_lds((const __attribute__((address_space(1))) u32*)g,
                                     (__attribute__((address_space(3))) u32*)l, 16, 0, 0);
}

// ---------------- prep: ALL weight conversions ----------------
__global__ void prep_all(const float* __restrict__ W_h2h, const float* __restrict__ W_i2h,
                         const float* __restrict__ W_ih, const float* __restrict__ W_hh,
                         const float* __restrict__ b_ih, const float* __restrict__ b_hh,
                         const float* __restrict__ W_gen,
                         char* __restrict__ Wh2h_q8, u16* __restrict__ Wi2h_bf,
                         u16* __restrict__ Wcat3, float* __restrict__ bsum,
                         u16* __restrict__ WgenP, float* __restrict__ WohT) {
    int idx = blockIdx.x * 256 + threadIdx.x;  // 65536 threads
    if (idx < 65536) {
        Wh2h_q8[idx] = (char)q8i(W_h2h[idx], SW);
        Wi2h_bf[idx] = f2bf(W_i2h[idx]);
    }
    for (int i = idx; i < 16 * 16 * 4 * 64 * 8; i += 65536) {
        int j = i & 7, lane = (i >> 3) & 63, q = (i >> 9) & 3, ks = (i >> 11) & 15, ub = i >> 15;
        int lr = lane & 15, lq = lane >> 4;
        int rg = q * 256 + ub * 16 + lr;
        int k = ks * 32 + lq * 8 + j;
        float v = (k < 256) ? W_ih[(size_t)rg * 356 + k] : W_hh[(size_t)rg * 256 + (k - 256)];
        Wcat3[i] = f2bf(v);
    }
    for (int i = idx; i < 100 * 1024; i += 65536) {
        int t = i >> 10, rg = i & 1023;
        WohT[i] = W_ih[(size_t)rg * 356 + 256 + t];
    }
    if (idx < 1024) bsum[idx] = b_ih[idx] + b_hh[idx];
    if (idx < 32768) {
        int r = idx >> 8, ccol = idx & 255;
        WgenP[idx] = (r < NCLS) ? f2bf(W_gen[r * 256 + ccol]) : (u16)0;
    }
}

// ---------------- proj_H GEMM: 1 batch/block, 128x256, 8 waves 2x4 --------
// Writes projF8 [b][h][t] int8 and bHf8 [b][t][i] int8 (direct, no transpose).
__launch_bounds__(512, 3)
__global__ void gemm_projH5(const float* __restrict__ bH, const u16* __restrict__ Wi2h_bf,
                            char* __restrict__ projF8, char* __restrict__ bHf8) {
    __shared__ char gsm[49152];
    u16* As[2] = {(u16*)gsm, (u16*)(gsm + 8192)};
    u16* Bs[2] = {(u16*)(gsm + 16384), (u16*)(gsm + 32768)};
    char* Tt = gsm;   // epilogue: [256 rows][144 pad] int8 (aliases As after final sync)

    int b = blockIdx.x, tid = threadIdx.x;
    int wave = tid >> 6, lane = tid & 63, lr = lane & 15, lq = lane >> 4;
    int wm = wave >> 2, wn = wave & 3;
    int ar = tid >> 2, part = tid & 3;
    const float* asrc = bH + ((size_t)b * 128 + ar) * 256 + part * 8;
    f32x4 acc[4][4] = {};
    uint2 bh[8];

    auto stageB = [&](int kc, int buf) {
        for (int i = 0; i < 2; i++) {
            int ch = wave * 2 + i;
            int row = ch * 16 + (lane >> 2);
            const u16* g = Wi2h_bf + (size_t)row * 256 + kc * 32 + (lane & 3) * 8;
            async_g2l(g, (char*)Bs[buf] + ch * 1024 + lane * 16);
        }
    };
    auto writeA = [&](int kc, int buf, float4 v0, float4 v1) {
        u16* dst = As[buf] + ar * 32 + part * 8;
        dst[0] = f2bf(v0.x); dst[1] = f2bf(v0.y); dst[2] = f2bf(v0.z); dst[3] = f2bf(v0.w);
        dst[4] = f2bf(v1.x); dst[5] = f2bf(v1.y); dst[6] = f2bf(v1.z); dst[7] = f2bf(v1.w);
        uint p0 = (uint)(u8)q8i(v0.x, SH) | ((uint)(u8)q8i(v0.y, SH) << 8) |
                  ((uint)(u8)q8i(v0.z, SH) << 16) | ((uint)(u8)q8i(v0.w, SH) << 24);
        uint p1 = (uint)(u8)q8i(v1.x, SH) | ((uint)(u8)q8i(v1.y, SH) << 8) |
                  ((uint)(u8)q8i(v1.z, SH) << 16) | ((uint)(u8)q8i(v1.w, SH) << 24);
        bh[kc].x = p0; bh[kc].y = p1;
    };

    float4 a0 = *(const float4*)(asrc);
    float4 a1 = *(const float4*)(asrc + 4);
    stageB(0, 0);
    writeA(0, 0, a0, a1);
    __syncthreads();

    for (int kc = 0; kc < 8; kc++) {
        int cur = kc & 1, nxt = cur ^ 1;
        if (kc < 7) {
            stageB(kc + 1, nxt);
            a0 = *(const float4*)(asrc + (kc + 1) * 32);
            a1 = *(const float4*)(asrc + (kc + 1) * 32 + 4);
        }
        short8 af[4];
        for (int mi = 0; mi < 4; mi++)
            af[mi] = *(const short8*)(As[cur] + (wm * 64 + mi * 16 + lr) * 32 + lq * 8);
        for (int ni = 0; ni < 4; ni++) {
            short8 bf = *(const short8*)(Bs[cur] + (wn * 64 + ni * 16 + lr) * 32 + lq * 8);
            for (int mi = 0; mi < 4; mi++)
                acc[mi][ni] = __builtin_amdgcn_mfma_f32_16x16x32_bf16(af[mi], bf, acc[mi][ni], 0, 0, 0);
        }
        if (kc < 7) writeA(kc + 1, nxt, a0, a1);
        __syncthreads();
    }

    // bHf8 [b][t][i]: straight from the A-quant registers, coalesced uint2 stores.
    for (int kc = 0; kc < 8; kc++)
        *(uint2*)(bHf8 + (size_t)b * 32768 + ar * 256 + kc * 32 + part * 8) = bh[kc];

    // projF8 transpose epilogue (int8 [b][h][t])
    for (int mi = 0; mi < 4; mi++)
        for (int ni = 0; ni < 4; ni++) {
            int h = wn * 64 + ni * 16 + lr;
            int t = wm * 64 + mi * 16 + lq * 4;
            f32x4 v = acc[mi][ni];
            uint pk = (uint)(u8)q8i(v[0], SP) | ((uint)(u8)q8i(v[1], SP) << 8) |
                      ((uint)(u8)q8i(v[2], SP) << 16) | ((uint)(u8)q8i(v[3], SP) << 24);
            *(uint*)(Tt + h * 144 + t) = pk;
        }
    __syncthreads();
    {
        int hrow = tid >> 1, half = tid & 1;
        const char* src = Tt + hrow * 144 + half * 64;
        char* dst = projF8 + (size_t)b * 32768 + hrow * 128 + half * 64;
        uint4 v0 = *(const uint4*)(src);
        uint4 v1 = *(const uint4*)(src + 16);
        uint4 v2 = *(const uint4*)(src + 32);
        uint4 v3 = *(const uint4*)(src + 48);
        *(uint4*)(dst) = v0; *(uint4*)(dst + 16) = v1;
        *(uint4*)(dst + 32) = v2; *(uint4*)(dst + 48) = v3;
    }
}

// ---------------- persistent block-local step loop: 256 blocks x 512 threads ----------
// Wave-specialized overlap (R3 structure at the PROVEN 512-thread/<=128-VGPR shape):
// waves 0-3 (tid<256) run attention A-E for both batches; waves 4-7 stream the h-half
// of the gate GEMM (512 KB, L2-bound) across the SAME 4 barrier regions (one ub per
// wave per region, accumulators region-local -> no cross-barrier register carry).
// After E all 8 waves stream the ctx-half. Rationale: R2 vs R6 showed phase F is
// L2-BW-bound (~13 us/step) -- can't be faster, so make it concurrent with attn VALU.
#define OFF_BH   0          // [2][128][256] int8, t-major
#define OFF_XT   65536      // u16 [2][512]  X = [ctx;h]
#define OFF_ZB   67584      // 64B zero block (A-frag rows >=2)
#define OFF_PH   67648      // f32 [2][256]
#define OFF_GC   69696      // f32 [2][4][256]  ctx partials | ctx-gates (aliased)
#define OFF_GH   77888      // f32 [2][4][256]  h-gates
#define OFF_EP   86080      // f32 [2][128*4]   e partials
#define OFF_ES   90176      // f32 [2][128]     exp(e-m)
#define OFF_H8   91200      // char [2][256]
#define OFF_WS   91712      // f32 [256] W_score
#define OFF_B2   92736      // f32 [256] b_h2h
#define OFF_TG   93760      // int [2][26]
#define OFF_RI   94016      // f32 [2]
#define LDS_TOT  94080

__launch_bounds__(512, 1)
__global__ void step_loop5(const char* __restrict__ projF8, const char* __restrict__ bHf8,
                           const char* __restrict__ Wh2h_q8, const float* __restrict__ b_h2h,
                           const float* __restrict__ W_score, const u16* __restrict__ Wcat3,
                           const float* __restrict__ bsum, const float* __restrict__ WohT,
                           const int* __restrict__ text, u16* __restrict__ hbf_all) {
    __shared__ __align__(16) char Lm[LDS_TOT];
    u16* Xt = (u16*)(Lm + OFF_XT);
    u16* zb = (u16*)(Lm + OFF_ZB);
    float* phL = (float*)(Lm + OFF_PH);
    float* gcC = (float*)(Lm + OFF_GC);
    float* gcH = (float*)(Lm + OFF_GH);
    float* epL = (float*)(Lm + OFF_EP);
    float* esL = (float*)(Lm + OFF_ES);
    char* h8c = Lm + OFF_H8;
    float* wsL = (float*)(Lm + OFF_WS);
    float* b2L = (float*)(Lm + OFF_B2);
    int* tgL = (int*)(Lm + OFF_TG);
    float* riL = (float*)(Lm + OFF_RI);

    int blk = blockIdx.x, tid = threadIdx.x;
    int lane = tid & 63;
    int wv = tid >> 6;                       // wave 0..7
    int lr = lane & 15, lq = lane >> 4;
    bool isAttn = (tid < 256);
    // attn decomposition (tid<256)
    int tq = tid & 7, hg = (tid & 255) >> 3; // hg in [0,32)
    int wv4 = wv & 3;                        // wave within attn group
    // gemm decomposition (waves 4-7)
    int w4 = wv - 4;                         // 0..3

    // ---- prologue: stage bHf8 into LDS, init state ----
    {
        const uint4* bg = (const uint4*)(bHf8 + (size_t)blk * 65536);
#pragma unroll
        for (int q = 0; q < 8; q++) {
            int w = tid + q * 512;           // uint4 index in [0,4096)
            *(uint4*)(Lm + OFF_BH + w * 16) = bg[w];
        }
        if (tid < 128) *(uint*)(Lm + OFF_XT + 512 + tid * 4) = 0;               // Xt[0] h-half
        else if (tid < 256) *(uint*)(Lm + OFF_XT + 1536 + (tid - 128) * 4) = 0; // Xt[1] h-half
        if (tid < 16) *(uint*)(Lm + OFF_ZB + tid * 4) = 0;
        if (tid < 256) { wsL[tid] = W_score[tid]; b2L[tid] = b_h2h[tid]; }
        if (tid < 52) {
            int bb = tid >= 26, st = tid - bb * 26;
            tgL[bb * 26 + st] = text[(blk * 2 + bb) * NSTEP + st];
        }
    }
    __syncthreads();

    float c0 = 0.f, c1 = 0.f;   // c state for (b=0,b=1), u = tid (attn threads)

    // h-half gate GEMM for one ub (full ks 8..15), region-local accumulators
    auto hseg = [&](int r) {
        int ub = r * 4 + w4;
        const u16* xsrc = (lr < 2) ? (Xt + lr * 512) : zb;
        int xstep = (lr < 2) ? 1 : 0;
        f32x4 ac[4] = {};
        for (int ks = 8; ks < 16; ks++) {
            short8 af = *(const short8*)(xsrc + (ks * 32 + lq * 8) * xstep);
            const u16* wb = Wcat3 + (size_t)((ub * 16 + ks) * 4) * 512 + lane * 8;
#pragma unroll
            for (int g = 0; g < 4; g++)
                ac[g] = __builtin_amdgcn_mfma_f32_16x16x32_bf16(
                    af, *(const short8*)(wb + g * 512), ac[g], 0, 0, 0);
        }
        if (lq == 0) {
#pragma unroll
            for (int g = 0; g < 4; g++) {
                gcH[(0 * 4 + g) * 256 + ub * 16 + lr] = ac[g][0];
                gcH[(1 * 4 + g) * 256 + ub * 16 + lr] = ac[g][1];
            }
        }
    };

    for (int s = 0; s < NSTEP; s++) {
        // ---- region 1: phase A (attn, both batches) || hseg ub-set 0 ----
        if (isAttn) {
            int u = tid;
            float v0, v1;
            if (s == 0) {
                v0 = v1 = b2L[u];
            } else {
                const uint4* wrow = (const uint4*)(Wh2h_q8 + (size_t)u * 256);
                const uint4* hv0 = (const uint4*)(h8c);
                const uint4* hv1 = (const uint4*)(h8c + 256);
                int a0 = 0, a1 = 0;
#pragma unroll
                for (int k = 0; k < 16; k++) {
                    uint4 w = wrow[k];
                    uint4 ha = hv0[k];
                    uint4 hb = hv1[k];
#ifdef HAS_SDOT4
                    a0 = __builtin_amdgcn_sdot4((int)w.x, (int)ha.x, a0, false);
                    a0 = __builtin_amdgcn_sdot4((int)w.y, (int)ha.y, a0, false);
                    a0 = __builtin_amdgcn_sdot4((int)w.z, (int)ha.z, a0, false);
                    a0 = __builtin_amdgcn_sdot4((int)w.w, (int)ha.w, a0, false);
                    a1 = __builtin_amdgcn_sdot4((int)w.x, (int)hb.x, a1, false);
                    a1 = __builtin_amdgcn_sdot4((int)w.y, (int)hb.y, a1, false);
                    a1 = __builtin_amdgcn_sdot4((int)w.z, (int)hb.z, a1, false);
                    a1 = __builtin_amdgcn_sdot4((int)w.w, (int)hb.w, a1, false);
#else
                    uint wv_[4] = {w.x, w.y, w.z, w.w};
                    uint ha_[4] = {ha.x, ha.y, ha.z, ha.w};
                    uint hb_[4] = {hb.x, hb.y, hb.z, hb.w};
                    for (int c = 0; c < 4; c++)
                        for (int by = 0; by < 32; by += 8) {
                            a0 += (int)(char)(wv_[c] >> by) * (int)(char)(ha_[c] >> by);
                            a1 += (int)(char)(wv_[c] >> by) * (int)(char)(hb_[c] >> by);
                        }
#endif
                }
                v0 = (float)a0 * (1.f / (SW * S8)) + b2L[u];
                v1 = (float)a1 * (1.f / (SW * S8)) + b2L[u];
            }
            phL[u] = v0;
            phL[256 + u] = v1;
        } else {
            hseg(0);
        }
        __syncthreads();

        // ---- region 2: phase B e-loop (attn, both batches) || hseg ub-set 1 ----
        if (isAttn) {
            const __half2 c3 = __float2half2_rn(-0.0016249f), c2 = __float2half2_rn(0.031520f);
            const __half2 c1h = __float2half2_rn(-0.222110f), c0h = __float2half2_rn(0.962117f);
            const float inv = 1.f / SP;
            int t0e = tq * 16;
            for (int bb = 0; bb < 2; bb++) {
                __half2 acc2[8];
#pragma unroll
                for (int q = 0; q < 8; q++) acc2[q] = __float2half2_rn(0.f);
                const char* baseG = projF8 + (size_t)(blk * 2 + bb) * 32768 + t0e;
#pragma unroll
                for (int hh = 0; hh < 8; hh++) {
                    int R = hg * 8 + hh;
                    uint4 uu = *(const uint4*)(baseG + R * 128);
                    float phv = phL[bb * 256 + R];
                    __half2 wv2 = __float2half2_rn(wsL[R]);
                    uint wq[4] = {uu.x, uu.y, uu.z, uu.w};
#pragma unroll
                    for (int wi = 0; wi < 4; wi++) {
                        uint w = wq[wi];
#pragma unroll
                        for (int pp = 0; pp < 2; pp++) {
                            float xa = fmaf((float)(char)(w >> (pp * 16)), inv, phv);
                            float xb = fmaf((float)(char)(w >> (pp * 16 + 8)), inv, phv);
                            xa = fminf(fmaxf(xa, -3.0f), 3.0f);
                            xb = fminf(fmaxf(xb, -3.0f), 3.0f);
                            __half2 x = __floats2half2_rn(xa, xb);
                            __half2 u2 = __hmul2(x, x);
                            __half2 p = __hfma2(__hfma2(__hfma2(c3, u2, c2), u2, c1h), u2, c0h);
                            acc2[wi * 2 + pp] = __hfma2(__hmul2(x, p), wv2, acc2[wi * 2 + pp]);
                        }
                    }
                }
                float a16[16];
#pragma unroll
                for (int q = 0; q < 8; q++) {
                    a16[q * 2] = __low2float(acc2[q]);
                    a16[q * 2 + 1] = __high2float(acc2[q]);
                }
#pragma unroll
                for (int j = 0; j < 16; j++) {
                    float v = a16[j];
                    v += __shfl_xor(v, 8);
                    v += __shfl_xor(v, 16);
                    v += __shfl_xor(v, 32);
                    a16[j] = v;
                }
                if (lane < 8) {
                    int t0w = lane * 16;
#pragma unroll
                    for (int j = 0; j < 16; j++) epL[bb * 512 + (t0w + j) * 4 + wv4] = a16[j];
                }
            }
        } else {
            hseg(1);
        }
        __syncthreads();

        // ---- region 3: phase C softmax (waves 0,1: one batch each) || hseg ub-set 2 ----
        if (isAttn) {
            if (wv4 < 2) {
                int bb = wv4;
                int t0 = lane * 2;
                float e0 = 0.f, e1 = 0.f;
#pragma unroll
                for (int w = 0; w < 4; w++) {
                    e0 += epL[bb * 512 + t0 * 4 + w];
                    e1 += epL[bb * 512 + (t0 + 1) * 4 + w];
                }
                float m = fmaxf(e0, e1);
                for (int o = 32; o >= 1; o >>= 1) m = fmaxf(m, __shfl_xor(m, o));
                float x0 = __expf(e0 - m), x1 = __expf(e1 - m);
                float ss = x0 + x1;
                for (int o = 32; o >= 1; o >>= 1) ss += __shfl_xor(ss, o);
                esL[bb * 128 + t0] = x0; esL[bb * 128 + t0 + 1] = x1;
                if (lane == 0) riL[bb] = 1.f / ss;
            }
        } else {
            hseg(2);
        }
        __syncthreads();

        // ---- region 4: phase D context partials (attn, both batches) || hseg ub-set 3 ----
        if (isAttn) {
            int slice = tid >> 6, ig = tid & 63;   // t in [slice*32,+32), i = ig*4..+3
            for (int bb = 0; bb < 2; bb++) {
                const char* bsrc = Lm + OFF_BH + bb * 32768 + slice * 32 * 256 + ig * 4;
                const float* es = esL + bb * 128 + slice * 32;
                float a0 = 0.f, a1 = 0.f, a2 = 0.f, a3 = 0.f;
#pragma unroll
                for (int t = 0; t < 32; t++) {
                    float al = es[t];
                    uint v = *(const uint*)(bsrc + t * 256);
                    a0 += al * (float)(char)(v);
                    a1 += al * (float)(char)(v >> 8);
                    a2 += al * (float)(char)(v >> 16);
                    a3 += al * (float)(char)(v >> 24);
                }
                float* cp = gcC + (bb * 4 + slice) * 256 + ig * 4;
                cp[0] = a0; cp[1] = a1; cp[2] = a2; cp[3] = a3;
            }
        } else {
            hseg(3);
        }
        __syncthreads();

        // ---- phase E: reduce partials -> Xt ctx half (attn threads) ----
        if (isAttn) {
            int i = tid;
#pragma unroll
            for (int bb = 0; bb < 2; bb++) {
                float sm = gcC[(bb * 4 + 0) * 256 + i] + gcC[(bb * 4 + 1) * 256 + i] +
                           gcC[(bb * 4 + 2) * 256 + i] + gcC[(bb * 4 + 3) * 256 + i];
                Xt[bb * 512 + i] = f2bf(sm * riL[bb] * (1.f / SH));
            }
        }
        __syncthreads();

        // ---- phase F: ctx-half gate GEMM, all 8 waves, wave wv owns ub = 2wv,2wv+1 ----
        {
            const u16* xsrc = (lr < 2) ? (Xt + lr * 512) : zb;
            int xstep = (lr < 2) ? 1 : 0;
            f32x4 ac0[4] = {}, ac1[4] = {};
            int ub0 = wv * 2, ub1 = wv * 2 + 1;
#pragma unroll 4
            for (int ks = 0; ks < 8; ks++) {
                short8 af = *(const short8*)(xsrc + (ks * 32 + lq * 8) * xstep);
                const u16* wb0 = Wcat3 + (size_t)((ub0 * 16 + ks) * 4) * 512 + lane * 8;
                const u16* wb1 = Wcat3 + (size_t)((ub1 * 16 + ks) * 4) * 512 + lane * 8;
#pragma unroll
                for (int g = 0; g < 4; g++) {
                    ac0[g] = __builtin_amdgcn_mfma_f32_16x16x32_bf16(
                        af, *(const short8*)(wb0 + g * 512), ac0[g], 0, 0, 0);
                    ac1[g] = __builtin_amdgcn_mfma_f32_16x16x32_bf16(
                        af, *(const short8*)(wb1 + g * 512), ac1[g], 0, 0, 0);
                }
            }
            if (lq == 0) {
#pragma unroll
                for (int g = 0; g < 4; g++) {
                    gcC[(0 * 4 + g) * 256 + ub0 * 16 + lr] = ac0[g][0];
                    gcC[(1 * 4 + g) * 256 + ub0 * 16 + lr] = ac0[g][1];
                    gcC[(0 * 4 + g) * 256 + ub1 * 16 + lr] = ac1[g][0];
                    gcC[(1 * 4 + g) * 256 + ub1 * 16 + lr] = ac1[g][1];
                }
            }
        }
        __syncthreads();

        // ---- phase G: pointwise LSTM (attn threads, both batches) ----
        if (isAttn) {
            int u = tid;
            {
                int tgt = tgL[s];
                const float* wt = WohT + (size_t)tgt * 1024;
                float gi = gcC[(0 * 4 + 0) * 256 + u] + gcH[(0 * 4 + 0) * 256 + u] + bsum[u] + wt[u];
                float gf = gcC[(0 * 4 + 1) * 256 + u] + gcH[(0 * 4 + 1) * 256 + u] + bsum[256 + u] + wt[256 + u];
                float gg = gcC[(0 * 4 + 2) * 256 + u] + gcH[(0 * 4 + 2) * 256 + u] + bsum[512 + u] + wt[512 + u];
                float go = gcC[(0 * 4 + 3) * 256 + u] + gcH[(0 * 4 + 3) * 256 + u] + bsum[768 + u] + wt[768 + u];
                float cn = fast_sig(gf) * c0 + fast_sig(gi) * fast_tanh(gg);
                float hn = fast_sig(go) * fast_tanh(cn);
                c0 = cn;
                hbf_all[(size_t)s * NB * NH + (size_t)(blk * 2 + 0) * 256 + u] = f2bf(hn);
                h8c[u] = (char)q8i(hn, S8);
                Xt[256 + u] = f2bf(hn);
            }
            {
                int tgt = tgL[26 + s];
                const float* wt = WohT + (size_t)tgt * 1024;
                float gi = gcC[(1 * 4 + 0) * 256 + u] + gcH[(1 * 4 + 0) * 256 + u] + bsum[u] + wt[u];
                float gf = gcC[(1 * 4 + 1) * 256 + u] + gcH[(1 * 4 + 1) * 256 + u] + bsum[256 + u] + wt[256 + u];
                float gg = gcC[(1 * 4 + 2) * 256 + u] + gcH[(1 * 4 + 2) * 256 + u] + bsum[512 + u] + wt[512 + u];
                float go = gcC[(1 * 4 + 3) * 256 + u] + gcH[(1 * 4 + 3) * 256 + u] + bsum[768 + u] + wt[768 + u];
                float cn = fast_sig(gf) * c1 + fast_sig(gi) * fast_tanh(gg);
                float hn = fast_sig(go) * fast_tanh(cn);
                c1 = cn;
                hbf_all[(size_t)s * NB * NH + (size_t)(blk * 2 + 1) * 256 + u] = f2bf(hn);
                h8c[256 + u] = (char)q8i(hn, S8);
                Xt[512 + 256 + u] = f2bf(hn);
            }
        }
        __syncthreads();
    }
}

// ---------------- final logits ----------------
__launch_bounds__(256)
__global__ void gen_logits(const u16* __restrict__ hbf_all, const u16* __restrict__ WgenP,
                           const float* __restrict__ b_gen, float* __restrict__ out) {
    __shared__ u16 As[32 * 32];
    __shared__ u16 Bs[128 * 32];
    int mb = blockIdx.x;
    int tid = threadIdx.x;
    int wave = tid >> 6, lane = tid & 63, lr = lane & 15, lq = lane >> 4;
    int wm = wave >> 1, wn = wave & 1;
    f32x4 acc[4] = {};
    for (int kc = 0; kc < 256; kc += 32) {
        __syncthreads();
        {
            int r = tid >> 3, c4 = (tid & 7) * 4;
            *(ushort4*)(As + r * 32 + c4) =
                *(const ushort4*)(hbf_all + (size_t)(mb * 32 + r) * 256 + kc + c4);
        }
        {
            int r = tid >> 1, h16 = (tid & 1) * 16;
            const u16* src = WgenP + (size_t)r * 256 + kc + h16;
            u16* d = Bs + r * 32 + h16;
            *(ushort4*)(d) = *(const ushort4*)(src);
            *(ushort4*)(d + 4) = *(const ushort4*)(src + 4);
            *(ushort4*)(d + 8) = *(const ushort4*)(src + 8);
            *(ushort4*)(d + 12) = *(const ushort4*)(src + 12);
        }
        __syncthreads();
        short8 a = *reinterpret_cast<const short8*>(As + (wm * 16 + lr) * 32 + lq * 8);
        for (int ni = 0; ni < 4; ni++) {
            short8 bb = *reinterpret_cast<const short8*>(Bs + (wn * 64 + ni * 16 + lr) * 32 + lq * 8);
            acc[ni] = __builtin_amdgcn_mfma_f32_16x16x32_bf16(a, bb, acc[ni], 0, 0, 0);
        }
    }
    for (int ni = 0; ni < 4; ni++) {
        int cidx = wn * 64 + ni * 16 + lr;
        if (cidx >= NCLS) continue;
        float bg = b_gen[cidx];
        int mbase = mb * 32 + wm * 16 + lq * 4;
        for (int r = 0; r < 4; r++) {
            int mm = mbase + r;
            int s = mm >> 9;
            int bb_ = mm & 511;
            float v = (cidx == 3) ? -10000.f : (acc[ni][r] + bg);
            out[(size_t)bb_ * (NSTEP * NCLS) + s * NCLS + cidx] = v;
        }
    }
}

extern "C" void kernel_launch(void* const* d_in, const int* in_sizes, int n_in,
                              void* d_out, int out_size, void* d_ws, size_t ws_size,
                              hipStream_t stream) {
    const float* batch_H = (const float*)d_in[0];
    const int* text = (const int*)d_in[1];
    const float* W_i2h = (const float*)d_in[3];
    const float* W_h2h = (const float*)d_in[4];
    const float* b_h2h = (const float*)d_in[5];
    const float* W_score = (const float*)d_in[6];
    const float* W_ih = (const float*)d_in[7];
    const float* W_hh = (const float*)d_in[8];
    const float* b_ih = (const float*)d_in[9];
    const float* b_hh = (const float*)d_in[10];
    const float* W_gen = (const float*)d_in[11];
    const float* b_gen = (const float*)d_in[12];
    float* out = (float*)d_out;

    char* ws = (char*)d_ws;
    size_t off = 0;
    auto alloc = [&](size_t bytes) {
        void* p = ws + off;
        off += (bytes + 255) & ~(size_t)255;
        return p;
    };
    char* projF8 = (char*)alloc((size_t)16777216);    // [b][h][t] int8
    char* bHf8 = (char*)alloc((size_t)16777216);      // [b][t][i] int8
    char* Wh2h_q8 = (char*)alloc(65536);
    u16* Wi2h_bf = (u16*)alloc(65536 * 2);
    u16* Wcat3 = (u16*)alloc((size_t)524288 * 2);     // frag-swizzled LSTM weights
    float* bsum = (float*)alloc(1024 * 4);
    u16* WgenP = (u16*)alloc(32768 * 2);
    float* WohT = (float*)alloc((size_t)102400 * 4);  // [100][1024]
    u16* hbf_all = (u16*)alloc((size_t)NSTEP * NB * NH * 2);

    prep_all<<<256, 256, 0, stream>>>(W_h2h, W_i2h, W_ih, W_hh, b_ih, b_hh, W_gen,
                                      Wh2h_q8, Wi2h_bf, Wcat3, bsum, WgenP, WohT);
    gemm_projH5<<<512, 512, 0, stream>>>(batch_H, Wi2h_bf, projF8, bHf8);
    step_loop5<<<256, 512, 0, stream>>>(projF8, bHf8, Wh2h_q8, b_h2h, W_score,
                                        Wcat3, bsum, WohT, text, hbf_all);
    gen_logits<<<416, 256, 0, stream>>>(hbf_all, WgenP, b_gen, out);
}

// Round 8
// 612.790 us; speedup vs baseline: 2.5025x; 2.5025x over previous
//
#include <hip/hip_runtime.h>
#include <hip/hip_fp16.h>
#include <stdint.h>

typedef unsigned short u16;
typedef unsigned char u8;
typedef unsigned int u32;
typedef __attribute__((ext_vector_type(8))) short short8;
typedef __attribute__((ext_vector_type(4))) float f32x4;

#define NSTEP 26
#define NB 512
#define NT 128
#define NH 256
#define NCLS 100

#define SP 32.0f     // proj_H int8 scale
#define SH 24.0f     // batch_H int8 scale
#define SW 2000.0f   // W_h2h int8 scale
#define S8 127.0f    // h int8 scale

#if defined(__has_builtin)
#if __has_builtin(__builtin_amdgcn_sdot4)
#define HAS_SDOT4 1
#endif
#endif

__device__ __forceinline__ u16 f2bf(float f) {
    unsigned u = __float_as_uint(f);
    return (u16)((u + 0x7FFFu + ((u >> 16) & 1u)) >> 16);
}
__device__ __forceinline__ int q8i(float x, float s) {
    float v = fminf(fmaxf(x * s, -127.f), 127.f);
    return __float2int_rn(v);
}
__device__ __forceinline__ float fast_tanh(float x) {
    float e = __expf(2.f * x);
    return 1.f - 2.f / (e + 1.f);
}
__device__ __forceinline__ float fast_sig(float x) { return 1.f / (1.f + __expf(-x)); }
__device__ __forceinline__ void async_g2l(const void* g, void* l) {
    __builtin_amdgcn_global_load_lds((const __attribute__((address_space(1))) u32*)g,
                                     (__attribute__((address_space(3))) u32*)l, 16, 0, 0);
}

// ---------------- prep: ALL weight conversions ----------------
__global__ void prep_all(const float* __restrict__ W_h2h, const float* __restrict__ W_i2h,
                         const float* __restrict__ W_ih, const float* __restrict__ W_hh,
                         const float* __restrict__ b_ih, const float* __restrict__ b_hh,
                         const float* __restrict__ W_gen,
                         char* __restrict__ Wh2h_q8, u16* __restrict__ Wi2h_bf,
                         u16* __restrict__ Wcat3, float* __restrict__ bsum,
                         u16* __restrict__ WgenP, float* __restrict__ WohT) {
    int idx = blockIdx.x * 256 + threadIdx.x;  // 65536 threads
    if (idx < 65536) {
        Wh2h_q8[idx] = (char)q8i(W_h2h[idx], SW);
        Wi2h_bf[idx] = f2bf(W_i2h[idx]);
    }
    for (int i = idx; i < 16 * 16 * 4 * 64 * 8; i += 65536) {
        int j = i & 7, lane = (i >> 3) & 63, q = (i >> 9) & 3, ks = (i >> 11) & 15, ub = i >> 15;
        int lr = lane & 15, lq = lane >> 4;
        int rg = q * 256 + ub * 16 + lr;
        int k = ks * 32 + lq * 8 + j;
        float v = (k < 256) ? W_ih[(size_t)rg * 356 + k] : W_hh[(size_t)rg * 256 + (k - 256)];
        Wcat3[i] = f2bf(v);
    }
    for (int i = idx; i < 100 * 1024; i += 65536) {
        int t = i >> 10, rg = i & 1023;
        WohT[i] = W_ih[(size_t)rg * 356 + 256 + t];
    }
    if (idx < 1024) bsum[idx] = b_ih[idx] + b_hh[idx];
    if (idx < 32768) {
        int r = idx >> 8, ccol = idx & 255;
        WgenP[idx] = (r < NCLS) ? f2bf(W_gen[r * 256 + ccol]) : (u16)0;
    }
}

// ---------------- proj_H GEMM: 1 batch/block, 128x256, 8 waves 2x4 --------
// Writes projF8 [b][h][t] int8 and bHf8 [b][t][i] int8 (direct, no transpose).
__launch_bounds__(512, 3)
__global__ void gemm_projH5(const float* __restrict__ bH, const u16* __restrict__ Wi2h_bf,
                            char* __restrict__ projF8, char* __restrict__ bHf8) {
    __shared__ char gsm[49152];
    u16* As[2] = {(u16*)gsm, (u16*)(gsm + 8192)};
    u16* Bs[2] = {(u16*)(gsm + 16384), (u16*)(gsm + 32768)};
    char* Tt = gsm;   // epilogue: [256 rows][144 pad] int8 (aliases As after final sync)

    int b = blockIdx.x, tid = threadIdx.x;
    int wave = tid >> 6, lane = tid & 63, lr = lane & 15, lq = lane >> 4;
    int wm = wave >> 2, wn = wave & 3;
    int ar = tid >> 2, part = tid & 3;
    const float* asrc = bH + ((size_t)b * 128 + ar) * 256 + part * 8;
    f32x4 acc[4][4] = {};
    uint2 bh[8];

    auto stageB = [&](int kc, int buf) {
        for (int i = 0; i < 2; i++) {
            int ch = wave * 2 + i;
            int row = ch * 16 + (lane >> 2);
            const u16* g = Wi2h_bf + (size_t)row * 256 + kc * 32 + (lane & 3) * 8;
            async_g2l(g, (char*)Bs[buf] + ch * 1024 + lane * 16);
        }
    };
    auto writeA = [&](int kc, int buf, float4 v0, float4 v1) {
        u16* dst = As[buf] + ar * 32 + part * 8;
        dst[0] = f2bf(v0.x); dst[1] = f2bf(v0.y); dst[2] = f2bf(v0.z); dst[3] = f2bf(v0.w);
        dst[4] = f2bf(v1.x); dst[5] = f2bf(v1.y); dst[6] = f2bf(v1.z); dst[7] = f2bf(v1.w);
        uint p0 = (uint)(u8)q8i(v0.x, SH) | ((uint)(u8)q8i(v0.y, SH) << 8) |
                  ((uint)(u8)q8i(v0.z, SH) << 16) | ((uint)(u8)q8i(v0.w, SH) << 24);
        uint p1 = (uint)(u8)q8i(v1.x, SH) | ((uint)(u8)q8i(v1.y, SH) << 8) |
                  ((uint)(u8)q8i(v1.z, SH) << 16) | ((uint)(u8)q8i(v1.w, SH) << 24);
        bh[kc].x = p0; bh[kc].y = p1;
    };

    float4 a0 = *(const float4*)(asrc);
    float4 a1 = *(const float4*)(asrc + 4);
    stageB(0, 0);
    writeA(0, 0, a0, a1);
    __syncthreads();

    for (int kc = 0; kc < 8; kc++) {
        int cur = kc & 1, nxt = cur ^ 1;
        if (kc < 7) {
            stageB(kc + 1, nxt);
            a0 = *(const float4*)(asrc + (kc + 1) * 32);
            a1 = *(const float4*)(asrc + (kc + 1) * 32 + 4);
        }
        short8 af[4];
        for (int mi = 0; mi < 4; mi++)
            af[mi] = *(const short8*)(As[cur] + (wm * 64 + mi * 16 + lr) * 32 + lq * 8);
        for (int ni = 0; ni < 4; ni++) {
            short8 bf = *(const short8*)(Bs[cur] + (wn * 64 + ni * 16 + lr) * 32 + lq * 8);
            for (int mi = 0; mi < 4; mi++)
                acc[mi][ni] = __builtin_amdgcn_mfma_f32_16x16x32_bf16(af[mi], bf, acc[mi][ni], 0, 0, 0);
        }
        if (kc < 7) writeA(kc + 1, nxt, a0, a1);
        __syncthreads();
    }

    // bHf8 [b][t][i]: straight from the A-quant registers, coalesced uint2 stores.
    for (int kc = 0; kc < 8; kc++)
        *(uint2*)(bHf8 + (size_t)b * 32768 + ar * 256 + kc * 32 + part * 8) = bh[kc];

    // projF8 transpose epilogue (int8 [b][h][t])
    for (int mi = 0; mi < 4; mi++)
        for (int ni = 0; ni < 4; ni++) {
            int h = wn * 64 + ni * 16 + lr;
            int t = wm * 64 + mi * 16 + lq * 4;
            f32x4 v = acc[mi][ni];
            uint pk = (uint)(u8)q8i(v[0], SP) | ((uint)(u8)q8i(v[1], SP) << 8) |
                      ((uint)(u8)q8i(v[2], SP) << 16) | ((uint)(u8)q8i(v[3], SP) << 24);
            *(uint*)(Tt + h * 144 + t) = pk;
        }
    __syncthreads();
    {
        int hrow = tid >> 1, half = tid & 1;
        const char* src = Tt + hrow * 144 + half * 64;
        char* dst = projF8 + (size_t)b * 32768 + hrow * 128 + half * 64;
        uint4 v0 = *(const uint4*)(src);
        uint4 v1 = *(const uint4*)(src + 16);
        uint4 v2 = *(const uint4*)(src + 32);
        uint4 v3 = *(const uint4*)(src + 48);
        *(uint4*)(dst) = v0; *(uint4*)(dst + 16) = v1;
        *(uint4*)(dst + 32) = v2; *(uint4*)(dst + 48) = v3;
    }
}

// ---------------- persistent block-local step loop: 256 blocks x 512 threads ----------
// R2 base (projF8+bHf8 both LDS-resident, proven 528us) + compressed-burst overlap:
// region1 = {waves 0-3: attn A+B for BOTH batches (A->B is intra-wave 8-lane comms,
// lgkmcnt fence only)} || {waves 4-7: h-half gate GEMM, ALL 16 ub back-to-back}.
// Phase F then streams only the ctx half. R7 lesson: the weight sweep must stay
// temporally compressed and must not share L2 with a projF8 stream, else L2 thrash
// (projF8 evicted every step -> 547MB HBM). Here projF8 is in LDS: no competing stream.
#define OFF_PROJ 0          // [2][256][128] int8, t-chunk XOR swizzled
#define OFF_BH   65536      // [2][128][256] int8, t-major
#define OFF_XT   131072     // u16 [2][512]  X = [ctx;h]
#define OFF_ZB   133120     // 64B zero block (A-frag rows >=2)
#define OFF_PH   133184     // f32 [2][256]
#define OFF_GC   135232     // f32 [2][4][256]  ctx partials | ctx-gates (aliased)
#define OFF_GH   143424     // f32 [2][4][256]  h-gates (written by burst)
#define OFF_EP   151616     // f32 [2][128*4]   e partials
#define OFF_ES   155712     // f32 [2][128]     exp(e-m)
#define OFF_H8   156736     // char [2][256]
#define OFF_WS   157248     // f32 [256] W_score
#define OFF_B2   158272     // f32 [256] b_h2h
#define OFF_TG   159296     // int [2][26]
#define OFF_RI   159552     // f32 [2]
#define LDS_TOT  159616

__launch_bounds__(512, 1)
__global__ void step_loop6(const char* __restrict__ projF8, const char* __restrict__ bHf8,
                           const char* __restrict__ Wh2h_q8, const float* __restrict__ b_h2h,
                           const float* __restrict__ W_score, const u16* __restrict__ Wcat3,
                           const float* __restrict__ bsum, const float* __restrict__ WohT,
                           const int* __restrict__ text, u16* __restrict__ hbf_all) {
    __shared__ __align__(16) char Lm[LDS_TOT];
    u16* Xt = (u16*)(Lm + OFF_XT);
    u16* zb = (u16*)(Lm + OFF_ZB);
    float* phL = (float*)(Lm + OFF_PH);
    float* gcC = (float*)(Lm + OFF_GC);
    float* gcH = (float*)(Lm + OFF_GH);
    float* epL = (float*)(Lm + OFF_EP);
    float* esL = (float*)(Lm + OFF_ES);
    char* h8c = Lm + OFF_H8;
    float* wsL = (float*)(Lm + OFF_WS);
    float* b2L = (float*)(Lm + OFF_B2);
    int* tgL = (int*)(Lm + OFF_TG);
    float* riL = (float*)(Lm + OFF_RI);

    int blk = blockIdx.x, tid = threadIdx.x;
    int lane = tid & 63;
    int wv = tid >> 6;                       // wave 0..7
    int lr = lane & 15, lq = lane >> 4;
    // attn decomposition (waves 0-3, tid<256): unit u = tid, both batches
    int tq = tid & 7, hg = (tid & 255) >> 3; // e-phase: t-chunk, h-group in [0,32)
    // D/E/G decomposition (512 threads): b = tid>>8, htid = tid&255
    int b = tid >> 8, htid = tid & 255;

    // ---- prologue: stage projF8 (swizzled) + bHf8 into LDS, init state ----
    {
        const uint4* pg = (const uint4*)(projF8 + (size_t)blk * 65536);
        const uint4* bg = (const uint4*)(bHf8 + (size_t)blk * 65536);
#pragma unroll
        for (int q = 0; q < 8; q++) {
            int w = tid + q * 512;           // uint4 index in [0,4096)
            int c = w & 7;                   // t-chunk
            int R = (w >> 3) & 255;          // h row
            int b2 = w >> 11;                // batch 0/1
            uint4 v = pg[w];
            *(uint4*)(Lm + OFF_PROJ + b2 * 32768 + R * 128 + (((c ^ (R >> 3)) & 7) << 4)) = v;
            *(uint4*)(Lm + OFF_BH + w * 16) = bg[w];
        }
        if (tid < 128) *(uint*)(Lm + OFF_XT + 512 + tid * 4) = 0;               // Xt[0] h-half
        else if (tid < 256) *(uint*)(Lm + OFF_XT + 1536 + (tid - 128) * 4) = 0; // Xt[1] h-half
        if (tid < 16) *(uint*)(Lm + OFF_ZB + tid * 4) = 0;
        if (tid < 256) { wsL[tid] = W_score[tid]; b2L[tid] = b_h2h[tid]; }
        if (tid < 52) {
            int bb = tid >= 26, st = tid - bb * 26;
            tgL[bb * 26 + st] = text[(blk * 2 + bb) * NSTEP + st];
        }
    }
    __syncthreads();

    float creg = 0.f;    // c state for (b = tid>>8, u = tid&255)

    for (int s = 0; s < NSTEP; s++) {
        // ================= region 1: attn A+B (waves 0-3) || h-burst (waves 4-7) ======
        if (wv < 4) {
            // ---- phase A: ph for both batches (unit u = tid) ----
            {
                int u = tid;
                float v0, v1;
                if (s == 0) {
                    v0 = v1 = b2L[u];
                } else {
                    const uint4* wrow = (const uint4*)(Wh2h_q8 + (size_t)u * 256);
                    const uint4* hv0 = (const uint4*)(h8c);
                    const uint4* hv1 = (const uint4*)(h8c + 256);
                    int a0 = 0, a1 = 0;
#pragma unroll
                    for (int k = 0; k < 16; k++) {
                        uint4 w = wrow[k];
                        uint4 ha = hv0[k];
                        uint4 hb = hv1[k];
#ifdef HAS_SDOT4
                        a0 = __builtin_amdgcn_sdot4((int)w.x, (int)ha.x, a0, false);
                        a0 = __builtin_amdgcn_sdot4((int)w.y, (int)ha.y, a0, false);
                        a0 = __builtin_amdgcn_sdot4((int)w.z, (int)ha.z, a0, false);
                        a0 = __builtin_amdgcn_sdot4((int)w.w, (int)ha.w, a0, false);
                        a1 = __builtin_amdgcn_sdot4((int)w.x, (int)hb.x, a1, false);
                        a1 = __builtin_amdgcn_sdot4((int)w.y, (int)hb.y, a1, false);
                        a1 = __builtin_amdgcn_sdot4((int)w.z, (int)hb.z, a1, false);
                        a1 = __builtin_amdgcn_sdot4((int)w.w, (int)hb.w, a1, false);
#else
                        uint wv_[4] = {w.x, w.y, w.z, w.w};
                        uint ha_[4] = {ha.x, ha.y, ha.z, ha.w};
                        uint hb_[4] = {hb.x, hb.y, hb.z, hb.w};
                        for (int c = 0; c < 4; c++)
                            for (int by = 0; by < 32; by += 8) {
                                a0 += (int)(char)(wv_[c] >> by) * (int)(char)(ha_[c] >> by);
                                a1 += (int)(char)(wv_[c] >> by) * (int)(char)(hb_[c] >> by);
                            }
#endif
                    }
                    v0 = (float)a0 * (1.f / (SW * S8)) + b2L[u];
                    v1 = (float)a1 * (1.f / (SW * S8)) + b2L[u];
                }
                phL[u] = v0;
                phL[256 + u] = v1;
            }
            // A->B communication is within each wave's 8-lane cluster: fence, no barrier
            asm volatile("s_waitcnt lgkmcnt(0)" ::: "memory");
            // ---- phase B: e-loop for both batches (LDS proj, swizzled) ----
            {
                const __half2 c3 = __float2half2_rn(-0.0016249f), c2 = __float2half2_rn(0.031520f);
                const __half2 c1h = __float2half2_rn(-0.222110f), c0h = __float2half2_rn(0.962117f);
                const float inv = 1.f / SP;
                int t0e = tq * 16;
                int co = ((tq ^ hg) & 7) << 4;   // swizzled chunk offset (R>>3 == hg)
                for (int bb = 0; bb < 2; bb++) {
                    __half2 acc2[8];
#pragma unroll
                    for (int q = 0; q < 8; q++) acc2[q] = __float2half2_rn(0.f);
                    const char* baseL = Lm + OFF_PROJ + bb * 32768 + co;
#pragma unroll
                    for (int hh = 0; hh < 8; hh++) {
                        int R = hg * 8 + hh;
                        uint4 uu = *(const uint4*)(baseL + R * 128);
                        float phv = phL[bb * 256 + R];
                        __half2 wv2 = __float2half2_rn(wsL[R]);
                        uint wq[4] = {uu.x, uu.y, uu.z, uu.w};
#pragma unroll
                        for (int wi = 0; wi < 4; wi++) {
                            uint w = wq[wi];
#pragma unroll
                            for (int pp = 0; pp < 2; pp++) {
                                float xa = fmaf((float)(char)(w >> (pp * 16)), inv, phv);
                                float xb = fmaf((float)(char)(w >> (pp * 16 + 8)), inv, phv);
                                xa = fminf(fmaxf(xa, -3.0f), 3.0f);
                                xb = fminf(fmaxf(xb, -3.0f), 3.0f);
                                __half2 x = __floats2half2_rn(xa, xb);
                                __half2 u2 = __hmul2(x, x);
                                __half2 p = __hfma2(__hfma2(__hfma2(c3, u2, c2), u2, c1h), u2, c0h);
                                acc2[wi * 2 + pp] = __hfma2(__hmul2(x, p), wv2, acc2[wi * 2 + pp]);
                            }
                        }
                    }
                    float a16[16];
#pragma unroll
                    for (int q = 0; q < 8; q++) {
                        a16[q * 2] = __low2float(acc2[q]);
                        a16[q * 2 + 1] = __high2float(acc2[q]);
                    }
#pragma unroll
                    for (int j = 0; j < 16; j++) {
                        float v = a16[j];
                        v += __shfl_xor(v, 8);
                        v += __shfl_xor(v, 16);
                        v += __shfl_xor(v, 32);
                        a16[j] = v;
                    }
                    if (lane < 8) {
                        int t0w = lane * 16;
#pragma unroll
                        for (int j = 0; j < 16; j++) epL[bb * 512 + (t0w + j) * 4 + wv] = a16[j];
                    }
                }
            }
        } else {
            // ---- h-burst: all 16 ub, ks 8..15, compressed into one window ----
            int w4 = wv - 4;
            const u16* xsrc = (lr < 2) ? (Xt + lr * 512) : zb;
            int xstep = (lr < 2) ? 1 : 0;
#pragma unroll
            for (int r = 0; r < 4; r++) {
                int ub = w4 * 4 + r;
                f32x4 ac[4] = {};
                for (int ks = 8; ks < 16; ks++) {
                    short8 af = *(const short8*)(xsrc + (ks * 32 + lq * 8) * xstep);
                    const u16* wb = Wcat3 + (size_t)((ub * 16 + ks) * 4) * 512 + lane * 8;
#pragma unroll
                    for (int g = 0; g < 4; g++)
                        ac[g] = __builtin_amdgcn_mfma_f32_16x16x32_bf16(
                            af, *(const short8*)(wb + g * 512), ac[g], 0, 0, 0);
                }
                if (lq == 0) {
#pragma unroll
                    for (int g = 0; g < 4; g++) {
                        gcH[(0 * 4 + g) * 256 + ub * 16 + lr] = ac[g][0];
                        gcH[(1 * 4 + g) * 256 + ub * 16 + lr] = ac[g][1];
                    }
                }
            }
        }
        __syncthreads();

        // ---- phase C: softmax (waves 0,1: one batch each) ----
        if (wv < 2) {
            int bb = wv;
            int t0 = lane * 2;
            float e0 = 0.f, e1 = 0.f;
#pragma unroll
            for (int w = 0; w < 4; w++) {
                e0 += epL[bb * 512 + t0 * 4 + w];
                e1 += epL[bb * 512 + (t0 + 1) * 4 + w];
            }
            float m = fmaxf(e0, e1);
            for (int o = 32; o >= 1; o >>= 1) m = fmaxf(m, __shfl_xor(m, o));
            float x0 = __expf(e0 - m), x1 = __expf(e1 - m);
            float ss = x0 + x1;
            for (int o = 32; o >= 1; o >>= 1) ss += __shfl_xor(ss, o);
            esL[bb * 128 + t0] = x0; esL[bb * 128 + t0 + 1] = x1;
            if (lane == 0) riL[bb] = 1.f / ss;
        }
        __syncthreads();

        // ---- phase D: context partials (all 8 waves; b = tid>>8) ----
        {
            int slice = htid >> 6, ig = htid & 63;   // t in [slice*32,+32), i = ig*4..+3
            const char* bsrc = Lm + OFF_BH + b * 32768 + slice * 32 * 256 + ig * 4;
            const float* es = esL + b * 128 + slice * 32;
            float a0 = 0.f, a1 = 0.f, a2 = 0.f, a3 = 0.f;
#pragma unroll
            for (int t = 0; t < 32; t++) {
                float al = es[t];
                uint v = *(const uint*)(bsrc + t * 256);
                a0 += al * (float)(char)(v);
                a1 += al * (float)(char)(v >> 8);
                a2 += al * (float)(char)(v >> 16);
                a3 += al * (float)(char)(v >> 24);
            }
            float* cp = gcC + (b * 4 + slice) * 256 + ig * 4;
            cp[0] = a0; cp[1] = a1; cp[2] = a2; cp[3] = a3;
        }
        __syncthreads();

        // ---- phase E: reduce partials -> Xt ctx half (bf16) ----
        {
            int i = htid;
            float sm = gcC[(b * 4 + 0) * 256 + i] + gcC[(b * 4 + 1) * 256 + i] +
                       gcC[(b * 4 + 2) * 256 + i] + gcC[(b * 4 + 3) * 256 + i];
            Xt[b * 512 + i] = f2bf(sm * riL[b] * (1.f / SH));
        }
        __syncthreads();

        // ---- phase F: ctx-half gate GEMM (ks 0..7), all 8 waves, ub = 2wv,2wv+1 ----
        {
            const u16* xsrc = (lr < 2) ? (Xt + lr * 512) : zb;
            int xstep = (lr < 2) ? 1 : 0;
            f32x4 ac0[4] = {}, ac1[4] = {};
            int ub0 = wv * 2, ub1 = wv * 2 + 1;
#pragma unroll 4
            for (int ks = 0; ks < 8; ks++) {
                short8 af = *(const short8*)(xsrc + (ks * 32 + lq * 8) * xstep);
                const u16* wb0 = Wcat3 + (size_t)((ub0 * 16 + ks) * 4) * 512 + lane * 8;
                const u16* wb1 = Wcat3 + (size_t)((ub1 * 16 + ks) * 4) * 512 + lane * 8;
#pragma unroll
                for (int g = 0; g < 4; g++) {
                    ac0[g] = __builtin_amdgcn_mfma_f32_16x16x32_bf16(
                        af, *(const short8*)(wb0 + g * 512), ac0[g], 0, 0, 0);
                    ac1[g] = __builtin_amdgcn_mfma_f32_16x16x32_bf16(
                        af, *(const short8*)(wb1 + g * 512), ac1[g], 0, 0, 0);
                }
            }
            if (lq == 0) {
#pragma unroll
                for (int g = 0; g < 4; g++) {
                    gcC[(0 * 4 + g) * 256 + ub0 * 16 + lr] = ac0[g][0];
                    gcC[(1 * 4 + g) * 256 + ub0 * 16 + lr] = ac0[g][1];
                    gcC[(0 * 4 + g) * 256 + ub1 * 16 + lr] = ac1[g][0];
                    gcC[(1 * 4 + g) * 256 + ub1 * 16 + lr] = ac1[g][1];
                }
            }
        }
        __syncthreads();

        // ---- phase G: pointwise LSTM (512 threads; b = tid>>8, u = htid) ----
        {
            int u = htid;
            int tgt = tgL[b * 26 + s];
            const float* wt = WohT + (size_t)tgt * 1024;
            float gi = gcC[(b * 4 + 0) * 256 + u] + gcH[(b * 4 + 0) * 256 + u] + bsum[u] + wt[u];
            float gf = gcC[(b * 4 + 1) * 256 + u] + gcH[(b * 4 + 1) * 256 + u] + bsum[256 + u] + wt[256 + u];
            float gg = gcC[(b * 4 + 2) * 256 + u] + gcH[(b * 4 + 2) * 256 + u] + bsum[512 + u] + wt[512 + u];
            float go = gcC[(b * 4 + 3) * 256 + u] + gcH[(b * 4 + 3) * 256 + u] + bsum[768 + u] + wt[768 + u];
            float cn = fast_sig(gf) * creg + fast_sig(gi) * fast_tanh(gg);
            float hn = fast_sig(go) * fast_tanh(cn);
            creg = cn;
            hbf_all[(size_t)s * NB * NH + (size_t)(blk * 2 + b) * 256 + u] = f2bf(hn);
            h8c[b * 256 + u] = (char)q8i(hn, S8);
            Xt[b * 512 + 256 + u] = f2bf(hn);
        }
        __syncthreads();
    }
}

// ---------------- final logits ----------------
__launch_bounds__(256)
__global__ void gen_logits(const u16* __restrict__ hbf_all, const u16* __restrict__ WgenP,
                           const float* __restrict__ b_gen, float* __restrict__ out) {
    __shared__ u16 As[32 * 32];
    __shared__ u16 Bs[128 * 32];
    int mb = blockIdx.x;
    int tid = threadIdx.x;
    int wave = tid >> 6, lane = tid & 63, lr = lane & 15, lq = lane >> 4;
    int wm = wave >> 1, wn = wave & 1;
    f32x4 acc[4] = {};
    for (int kc = 0; kc < 256; kc += 32) {
        __syncthreads();
        {
            int r = tid >> 3, c4 = (tid & 7) * 4;
            *(ushort4*)(As + r * 32 + c4) =
                *(const ushort4*)(hbf_all + (size_t)(mb * 32 + r) * 256 + kc + c4);
        }
        {
            int r = tid >> 1, h16 = (tid & 1) * 16;
            const u16* src = WgenP + (size_t)r * 256 + kc + h16;
            u16* d = Bs + r * 32 + h16;
            *(ushort4*)(d) = *(const ushort4*)(src);
            *(ushort4*)(d + 4) = *(const ushort4*)(src + 4);
            *(ushort4*)(d + 8) = *(const ushort4*)(src + 8);
            *(ushort4*)(d + 12) = *(const ushort4*)(src + 12);
        }
        __syncthreads();
        short8 a = *reinterpret_cast<const short8*>(As + (wm * 16 + lr) * 32 + lq * 8);
        for (int ni = 0; ni < 4; ni++) {
            short8 bb = *reinterpret_cast<const short8*>(Bs + (wn * 64 + ni * 16 + lr) * 32 + lq * 8);
            acc[ni] = __builtin_amdgcn_mfma_f32_16x16x32_bf16(a, bb, acc[ni], 0, 0, 0);
        }
    }
    for (int ni = 0; ni < 4; ni++) {
        int cidx = wn * 64 + ni * 16 + lr;
        if (cidx >= NCLS) continue;
        float bg = b_gen[cidx];
        int mbase = mb * 32 + wm * 16 + lq * 4;
        for (int r = 0; r < 4; r++) {
            int mm = mbase + r;
            int s = mm >> 9;
            int bb_ = mm & 511;
            float v = (cidx == 3) ? -10000.f : (acc[ni][r] + bg);
            out[(size_t)bb_ * (NSTEP * NCLS) + s * NCLS + cidx] = v;
        }
    }
}

extern "C" void kernel_launch(void* const* d_in, const int* in_sizes, int n_in,
                              void* d_out, int out_size, void* d_ws, size_t ws_size,
                              hipStream_t stream) {
    const float* batch_H = (const float*)d_in[0];
    const int* text = (const int*)d_in[1];
    const float* W_i2h = (const float*)d_in[3];
    const float* W_h2h = (const float*)d_in[4];
    const float* b_h2h = (const float*)d_in[5];
    const float* W_score = (const float*)d_in[6];
    const float* W_ih = (const float*)d_in[7];
    const float* W_hh = (const float*)d_in[8];
    const float* b_ih = (const float*)d_in[9];
    const float* b_hh = (const float*)d_in[10];
    const float* W_gen = (const float*)d_in[11];
    const float* b_gen = (const float*)d_in[12];
    float* out = (float*)d_out;

    char* ws = (char*)d_ws;
    size_t off = 0;
    auto alloc = [&](size_t bytes) {
        void* p = ws + off;
        off += (bytes + 255) & ~(size_t)255;
        return p;
    };
    char* projF8 = (char*)alloc((size_t)16777216);    // [b][h][t] int8
    char* bHf8 = (char*)alloc((size_t)16777216);      // [b][t][i] int8
    char* Wh2h_q8 = (char*)alloc(65536);
    u16* Wi2h_bf = (u16*)alloc(65536 * 2);
    u16* Wcat3 = (u16*)alloc((size_t)524288 * 2);     // frag-swizzled LSTM weights
    float* bsum = (float*)alloc(1024 * 4);
    u16* WgenP = (u16*)alloc(32768 * 2);
    float* WohT = (float*)alloc((size_t)102400 * 4);  // [100][1024]
    u16* hbf_all = (u16*)alloc((size_t)NSTEP * NB * NH * 2);

    prep_all<<<256, 256, 0, stream>>>(W_h2h, W_i2h, W_ih, W_hh, b_ih, b_hh, W_gen,
                                      Wh2h_q8, Wi2h_bf, Wcat3, bsum, WgenP, WohT);
    gemm_projH5<<<512, 512, 0, stream>>>(batch_H, Wi2h_bf, projF8, bHf8);
    step_loop6<<<256, 512, 0, stream>>>(projF8, bHf8, Wh2h_q8, b_h2h, W_score,
                                        Wcat3, bsum, WohT, text, hbf_all);
    gen_logits<<<416, 256, 0, stream>>>(hbf_all, WgenP, b_gen, out);
}

// Round 9
// 544.206 us; speedup vs baseline: 2.8179x; 1.1260x over previous
//
#include <hip/hip_runtime.h>
#include <hip/hip_fp16.h>
#include <stdint.h>

typedef unsigned short u16;
typedef unsigned char u8;
typedef unsigned int u32;
typedef __attribute__((ext_vector_type(8))) short short8;
typedef __attribute__((ext_vector_type(4))) float f32x4;

#define NSTEP 26
#define NB 512
#define NT 128
#define NH 256
#define NCLS 100

#define SP 32.0f     // proj_H int8 scale
#define SH 24.0f     // batch_H int8 scale
#define SW 2000.0f   // W_h2h int8 scale
#define S8 127.0f    // h int8 scale

#if defined(__has_builtin)
#if __has_builtin(__builtin_amdgcn_sdot4)
#define HAS_SDOT4 1
#endif
#endif

__device__ __forceinline__ u16 f2bf(float f) {
    unsigned u = __float_as_uint(f);
    return (u16)((u + 0x7FFFu + ((u >> 16) & 1u)) >> 16);
}
__device__ __forceinline__ int q8i(float x, float s) {
    float v = fminf(fmaxf(x * s, -127.f), 127.f);
    return __float2int_rn(v);
}
__device__ __forceinline__ float fast_tanh(float x) {
    float e = __expf(2.f * x);
    return 1.f - 2.f / (e + 1.f);
}
__device__ __forceinline__ float fast_sig(float x) { return 1.f / (1.f + __expf(-x)); }
__device__ __forceinline__ void async_g2l(const void* g, void* l) {
    __builtin_amdgcn_global_load_lds((const __attribute__((address_space(1))) u32*)g,
                                     (__attribute__((address_space(3))) u32*)l, 16, 0, 0);
}

// ---------------- prep: ALL weight conversions ----------------
__global__ void prep_all(const float* __restrict__ W_h2h, const float* __restrict__ W_i2h,
                         const float* __restrict__ W_ih, const float* __restrict__ W_hh,
                         const float* __restrict__ b_ih, const float* __restrict__ b_hh,
                         const float* __restrict__ W_gen,
                         char* __restrict__ Wh2h_q8, u16* __restrict__ Wi2h_bf,
                         u16* __restrict__ Wcat3, float* __restrict__ bsum,
                         u16* __restrict__ WgenP, float* __restrict__ WohT) {
    int idx = blockIdx.x * 256 + threadIdx.x;  // 65536 threads
    if (idx < 65536) {
        Wh2h_q8[idx] = (char)q8i(W_h2h[idx], SW);
        Wi2h_bf[idx] = f2bf(W_i2h[idx]);
    }
    for (int i = idx; i < 16 * 16 * 4 * 64 * 8; i += 65536) {
        int j = i & 7, lane = (i >> 3) & 63, q = (i >> 9) & 3, ks = (i >> 11) & 15, ub = i >> 15;
        int lr = lane & 15, lq = lane >> 4;
        int rg = q * 256 + ub * 16 + lr;
        int k = ks * 32 + lq * 8 + j;
        float v = (k < 256) ? W_ih[(size_t)rg * 356 + k] : W_hh[(size_t)rg * 256 + (k - 256)];
        Wcat3[i] = f2bf(v);
    }
    for (int i = idx; i < 100 * 1024; i += 65536) {
        int t = i >> 10, rg = i & 1023;
        WohT[i] = W_ih[(size_t)rg * 356 + 256 + t];
    }
    if (idx < 1024) bsum[idx] = b_ih[idx] + b_hh[idx];
    if (idx < 32768) {
        int r = idx >> 8, ccol = idx & 255;
        WgenP[idx] = (r < NCLS) ? f2bf(W_gen[r * 256 + ccol]) : (u16)0;
    }
}

// ---------------- proj_H GEMM: 1 batch/block, 128x256, 8 waves 2x4 --------
// Writes projF8 [b][h][t] int8 and bHf8 [b][t][i] int8 (direct, no transpose).
__launch_bounds__(512, 3)
__global__ void gemm_projH5(const float* __restrict__ bH, const u16* __restrict__ Wi2h_bf,
                            char* __restrict__ projF8, char* __restrict__ bHf8) {
    __shared__ char gsm[49152];
    u16* As[2] = {(u16*)gsm, (u16*)(gsm + 8192)};
    u16* Bs[2] = {(u16*)(gsm + 16384), (u16*)(gsm + 32768)};
    char* Tt = gsm;   // epilogue: [256 rows][144 pad] int8 (aliases As after final sync)

    int b = blockIdx.x, tid = threadIdx.x;
    int wave = tid >> 6, lane = tid & 63, lr = lane & 15, lq = lane >> 4;
    int wm = wave >> 2, wn = wave & 3;
    int ar = tid >> 2, part = tid & 3;
    const float* asrc = bH + ((size_t)b * 128 + ar) * 256 + part * 8;
    f32x4 acc[4][4] = {};
    uint2 bh[8];

    auto stageB = [&](int kc, int buf) {
        for (int i = 0; i < 2; i++) {
            int ch = wave * 2 + i;
            int row = ch * 16 + (lane >> 2);
            const u16* g = Wi2h_bf + (size_t)row * 256 + kc * 32 + (lane & 3) * 8;
            async_g2l(g, (char*)Bs[buf] + ch * 1024 + lane * 16);
        }
    };
    auto writeA = [&](int kc, int buf, float4 v0, float4 v1) {
        u16* dst = As[buf] + ar * 32 + part * 8;
        dst[0] = f2bf(v0.x); dst[1] = f2bf(v0.y); dst[2] = f2bf(v0.z); dst[3] = f2bf(v0.w);
        dst[4] = f2bf(v1.x); dst[5] = f2bf(v1.y); dst[6] = f2bf(v1.z); dst[7] = f2bf(v1.w);
        uint p0 = (uint)(u8)q8i(v0.x, SH) | ((uint)(u8)q8i(v0.y, SH) << 8) |
                  ((uint)(u8)q8i(v0.z, SH) << 16) | ((uint)(u8)q8i(v0.w, SH) << 24);
        uint p1 = (uint)(u8)q8i(v1.x, SH) | ((uint)(u8)q8i(v1.y, SH) << 8) |
                  ((uint)(u8)q8i(v1.z, SH) << 16) | ((uint)(u8)q8i(v1.w, SH) << 24);
        bh[kc].x = p0; bh[kc].y = p1;
    };

    float4 a0 = *(const float4*)(asrc);
    float4 a1 = *(const float4*)(asrc + 4);
    stageB(0, 0);
    writeA(0, 0, a0, a1);
    __syncthreads();

    for (int kc = 0; kc < 8; kc++) {
        int cur = kc & 1, nxt = cur ^ 1;
        if (kc < 7) {
            stageB(kc + 1, nxt);
            a0 = *(const float4*)(asrc + (kc + 1) * 32);
            a1 = *(const float4*)(asrc + (kc + 1) * 32 + 4);
        }
        short8 af[4];
        for (int mi = 0; mi < 4; mi++)
            af[mi] = *(const short8*)(As[cur] + (wm * 64 + mi * 16 + lr) * 32 + lq * 8);
        for (int ni = 0; ni < 4; ni++) {
            short8 bf = *(const short8*)(Bs[cur] + (wn * 64 + ni * 16 + lr) * 32 + lq * 8);
            for (int mi = 0; mi < 4; mi++)
                acc[mi][ni] = __builtin_amdgcn_mfma_f32_16x16x32_bf16(af[mi], bf, acc[mi][ni], 0, 0, 0);
        }
        if (kc < 7) writeA(kc + 1, nxt, a0, a1);
        __syncthreads();
    }

    // bHf8 [b][t][i]: straight from the A-quant registers, coalesced uint2 stores.
    for (int kc = 0; kc < 8; kc++)
        *(uint2*)(bHf8 + (size_t)b * 32768 + ar * 256 + kc * 32 + part * 8) = bh[kc];

    // projF8 transpose epilogue (int8 [b][h][t])
    for (int mi = 0; mi < 4; mi++)
        for (int ni = 0; ni < 4; ni++) {
            int h = wn * 64 + ni * 16 + lr;
            int t = wm * 64 + mi * 16 + lq * 4;
            f32x4 v = acc[mi][ni];
            uint pk = (uint)(u8)q8i(v[0], SP) | ((uint)(u8)q8i(v[1], SP) << 8) |
                      ((uint)(u8)q8i(v[2], SP) << 16) | ((uint)(u8)q8i(v[3], SP) << 24);
            *(uint*)(Tt + h * 144 + t) = pk;
        }
    __syncthreads();
    {
        int hrow = tid >> 1, half = tid & 1;
        const char* src = Tt + hrow * 144 + half * 64;
        char* dst = projF8 + (size_t)b * 32768 + hrow * 128 + half * 64;
        uint4 v0 = *(const uint4*)(src);
        uint4 v1 = *(const uint4*)(src + 16);
        uint4 v2 = *(const uint4*)(src + 32);
        uint4 v3 = *(const uint4*)(src + 48);
        *(uint4*)(dst) = v0; *(uint4*)(dst + 16) = v1;
        *(uint4*)(dst + 32) = v2; *(uint4*)(dst + 48) = v3;
    }
}

// ---------------- persistent block-local step loop: 256 blocks x 512 threads ----------
// R8 structure + PER-BLOCK STAGGER of the weight sweep. Diagnosis (R2/R6/R8): the
// Wcat3 stream is pinned at ~36 B/cy/CU by L2 same-line hotspotting -- all 32 CUs of
// an XCD, barrier-locked to the same ks, request the SAME cache line each cycle and
// serialize on one L2 bank. rot=(blk>>3)&15 gives same-XCD neighbors distinct sweep
// phases so requests spread across banks. Accumulation ORDER changes only (fp assoc).
#define OFF_PROJ 0          // [2][256][128] int8, t-chunk XOR swizzled
#define OFF_BH   65536      // [2][128][256] int8, t-major
#define OFF_XT   131072     // u16 [2][512]  X = [ctx;h]
#define OFF_ZB   133120     // 64B zero block (A-frag rows >=2)
#define OFF_PH   133184     // f32 [2][256]
#define OFF_GC   135232     // f32 [2][4][256]  ctx partials | ctx-gates (aliased)
#define OFF_GH   143424     // f32 [2][4][256]  h-gates (written by burst)
#define OFF_EP   151616     // f32 [2][128*4]   e partials
#define OFF_ES   155712     // f32 [2][128]     exp(e-m)
#define OFF_H8   156736     // char [2][256]
#define OFF_WS   157248     // f32 [256] W_score
#define OFF_B2   158272     // f32 [256] b_h2h
#define OFF_TG   159296     // int [2][26]
#define OFF_RI   159552     // f32 [2]
#define LDS_TOT  159616

__launch_bounds__(512, 1)
__global__ void step_loop7(const char* __restrict__ projF8, const char* __restrict__ bHf8,
                           const char* __restrict__ Wh2h_q8, const float* __restrict__ b_h2h,
                           const float* __restrict__ W_score, const u16* __restrict__ Wcat3,
                           const float* __restrict__ bsum, const float* __restrict__ WohT,
                           const int* __restrict__ text, u16* __restrict__ hbf_all) {
    __shared__ __align__(16) char Lm[LDS_TOT];
    u16* Xt = (u16*)(Lm + OFF_XT);
    u16* zb = (u16*)(Lm + OFF_ZB);
    float* phL = (float*)(Lm + OFF_PH);
    float* gcC = (float*)(Lm + OFF_GC);
    float* gcH = (float*)(Lm + OFF_GH);
    float* epL = (float*)(Lm + OFF_EP);
    float* esL = (float*)(Lm + OFF_ES);
    char* h8c = Lm + OFF_H8;
    float* wsL = (float*)(Lm + OFF_WS);
    float* b2L = (float*)(Lm + OFF_B2);
    int* tgL = (int*)(Lm + OFF_TG);
    float* riL = (float*)(Lm + OFF_RI);

    int blk = blockIdx.x, tid = threadIdx.x;
    int lane = tid & 63;
    int wv = tid >> 6;                       // wave 0..7
    int lr = lane & 15, lq = lane >> 4;
    int rot = (blk >> 3) & 15;               // sweep stagger (same-XCD blocks differ)
    int rot7 = rot & 7;
    // attn decomposition (waves 0-3, tid<256): unit u = tid, both batches
    int tq = tid & 7, hg = (tid & 255) >> 3; // e-phase: t-chunk, h-group in [0,32)
    // D/E/G decomposition (512 threads): b = tid>>8, htid = tid&255
    int b = tid >> 8, htid = tid & 255;

    // ---- prologue: stage projF8 (swizzled) + bHf8 into LDS, init state ----
    {
        const uint4* pg = (const uint4*)(projF8 + (size_t)blk * 65536);
        const uint4* bg = (const uint4*)(bHf8 + (size_t)blk * 65536);
#pragma unroll
        for (int q = 0; q < 8; q++) {
            int w = tid + q * 512;           // uint4 index in [0,4096)
            int c = w & 7;                   // t-chunk
            int R = (w >> 3) & 255;          // h row
            int b2 = w >> 11;                // batch 0/1
            uint4 v = pg[w];
            *(uint4*)(Lm + OFF_PROJ + b2 * 32768 + R * 128 + (((c ^ (R >> 3)) & 7) << 4)) = v;
            *(uint4*)(Lm + OFF_BH + w * 16) = bg[w];
        }
        if (tid < 128) *(uint*)(Lm + OFF_XT + 512 + tid * 4) = 0;               // Xt[0] h-half
        else if (tid < 256) *(uint*)(Lm + OFF_XT + 1536 + (tid - 128) * 4) = 0; // Xt[1] h-half
        if (tid < 16) *(uint*)(Lm + OFF_ZB + tid * 4) = 0;
        if (tid < 256) { wsL[tid] = W_score[tid]; b2L[tid] = b_h2h[tid]; }
        if (tid < 52) {
            int bb = tid >= 26, st = tid - bb * 26;
            tgL[bb * 26 + st] = text[(blk * 2 + bb) * NSTEP + st];
        }
    }
    __syncthreads();

    float creg = 0.f;    // c state for (b = tid>>8, u = tid&255)

    for (int s = 0; s < NSTEP; s++) {
        // ================= region 1: attn A+B (waves 0-3) || h-burst (waves 4-7) ======
        if (wv < 4) {
            // ---- phase A: ph for both batches (unit u = tid) ----
            {
                int u = tid;
                float v0, v1;
                if (s == 0) {
                    v0 = v1 = b2L[u];
                } else {
                    const uint4* wrow = (const uint4*)(Wh2h_q8 + (size_t)u * 256);
                    const uint4* hv0 = (const uint4*)(h8c);
                    const uint4* hv1 = (const uint4*)(h8c + 256);
                    int a0 = 0, a1 = 0;
#pragma unroll
                    for (int k = 0; k < 16; k++) {
                        uint4 w = wrow[k];
                        uint4 ha = hv0[k];
                        uint4 hb = hv1[k];
#ifdef HAS_SDOT4
                        a0 = __builtin_amdgcn_sdot4((int)w.x, (int)ha.x, a0, false);
                        a0 = __builtin_amdgcn_sdot4((int)w.y, (int)ha.y, a0, false);
                        a0 = __builtin_amdgcn_sdot4((int)w.z, (int)ha.z, a0, false);
                        a0 = __builtin_amdgcn_sdot4((int)w.w, (int)ha.w, a0, false);
                        a1 = __builtin_amdgcn_sdot4((int)w.x, (int)hb.x, a1, false);
                        a1 = __builtin_amdgcn_sdot4((int)w.y, (int)hb.y, a1, false);
                        a1 = __builtin_amdgcn_sdot4((int)w.z, (int)hb.z, a1, false);
                        a1 = __builtin_amdgcn_sdot4((int)w.w, (int)hb.w, a1, false);
#else
                        uint wv_[4] = {w.x, w.y, w.z, w.w};
                        uint ha_[4] = {ha.x, ha.y, ha.z, ha.w};
                        uint hb_[4] = {hb.x, hb.y, hb.z, hb.w};
                        for (int c = 0; c < 4; c++)
                            for (int by = 0; by < 32; by += 8) {
                                a0 += (int)(char)(wv_[c] >> by) * (int)(char)(ha_[c] >> by);
                                a1 += (int)(char)(wv_[c] >> by) * (int)(char)(hb_[c] >> by);
                            }
#endif
                    }
                    v0 = (float)a0 * (1.f / (SW * S8)) + b2L[u];
                    v1 = (float)a1 * (1.f / (SW * S8)) + b2L[u];
                }
                phL[u] = v0;
                phL[256 + u] = v1;
            }
            // A->B communication is within each wave's 8-lane cluster: fence, no barrier
            asm volatile("s_waitcnt lgkmcnt(0)" ::: "memory");
            // ---- phase B: e-loop for both batches (LDS proj, swizzled) ----
            {
                const __half2 c3 = __float2half2_rn(-0.0016249f), c2 = __float2half2_rn(0.031520f);
                const __half2 c1h = __float2half2_rn(-0.222110f), c0h = __float2half2_rn(0.962117f);
                const float inv = 1.f / SP;
                int t0e = tq * 16;
                int co = ((tq ^ hg) & 7) << 4;   // swizzled chunk offset (R>>3 == hg)
                for (int bb = 0; bb < 2; bb++) {
                    __half2 acc2[8];
#pragma unroll
                    for (int q = 0; q < 8; q++) acc2[q] = __float2half2_rn(0.f);
                    const char* baseL = Lm + OFF_PROJ + bb * 32768 + co;
#pragma unroll
                    for (int hh = 0; hh < 8; hh++) {
                        int R = hg * 8 + hh;
                        uint4 uu = *(const uint4*)(baseL + R * 128);
                        float phv = phL[bb * 256 + R];
                        __half2 wv2 = __float2half2_rn(wsL[R]);
                        uint wq[4] = {uu.x, uu.y, uu.z, uu.w};
#pragma unroll
                        for (int wi = 0; wi < 4; wi++) {
                            uint w = wq[wi];
#pragma unroll
                            for (int pp = 0; pp < 2; pp++) {
                                float xa = fmaf((float)(char)(w >> (pp * 16)), inv, phv);
                                float xb = fmaf((float)(char)(w >> (pp * 16 + 8)), inv, phv);
                                xa = fminf(fmaxf(xa, -3.0f), 3.0f);
                                xb = fminf(fmaxf(xb, -3.0f), 3.0f);
                                __half2 x = __floats2half2_rn(xa, xb);
                                __half2 u2 = __hmul2(x, x);
                                __half2 p = __hfma2(__hfma2(__hfma2(c3, u2, c2), u2, c1h), u2, c0h);
                                acc2[wi * 2 + pp] = __hfma2(__hmul2(x, p), wv2, acc2[wi * 2 + pp]);
                            }
                        }
                    }
                    float a16[16];
#pragma unroll
                    for (int q = 0; q < 8; q++) {
                        a16[q * 2] = __low2float(acc2[q]);
                        a16[q * 2 + 1] = __high2float(acc2[q]);
                    }
#pragma unroll
                    for (int j = 0; j < 16; j++) {
                        float v = a16[j];
                        v += __shfl_xor(v, 8);
                        v += __shfl_xor(v, 16);
                        v += __shfl_xor(v, 32);
                        a16[j] = v;
                    }
                    if (lane < 8) {
                        int t0w = lane * 16;
#pragma unroll
                        for (int j = 0; j < 16; j++) epL[bb * 512 + (t0w + j) * 4 + wv] = a16[j];
                    }
                }
            }
        } else {
            // ---- h-burst: all 16 ub, ks 8..15, STAGGERED sweep order per block ----
            int w4 = wv - 4;
            const u16* xsrc = (lr < 2) ? (Xt + lr * 512) : zb;
            int xstep = (lr < 2) ? 1 : 0;
#pragma unroll
            for (int r = 0; r < 4; r++) {
                int ub = (w4 * 4 + r + rot) & 15;
                f32x4 ac[4] = {};
                for (int kk = 0; kk < 8; kk++) {
                    int ks = 8 + ((kk + rot) & 7);
                    short8 af = *(const short8*)(xsrc + (ks * 32 + lq * 8) * xstep);
                    const u16* wb = Wcat3 + (size_t)((ub * 16 + ks) * 4) * 512 + lane * 8;
#pragma unroll
                    for (int g = 0; g < 4; g++)
                        ac[g] = __builtin_amdgcn_mfma_f32_16x16x32_bf16(
                            af, *(const short8*)(wb + g * 512), ac[g], 0, 0, 0);
                }
                if (lq == 0) {
#pragma unroll
                    for (int g = 0; g < 4; g++) {
                        gcH[(0 * 4 + g) * 256 + ub * 16 + lr] = ac[g][0];
                        gcH[(1 * 4 + g) * 256 + ub * 16 + lr] = ac[g][1];
                    }
                }
            }
        }
        __syncthreads();

        // ---- phase C: softmax (waves 0,1: one batch each) ----
        if (wv < 2) {
            int bb = wv;
            int t0 = lane * 2;
            float e0 = 0.f, e1 = 0.f;
#pragma unroll
            for (int w = 0; w < 4; w++) {
                e0 += epL[bb * 512 + t0 * 4 + w];
                e1 += epL[bb * 512 + (t0 + 1) * 4 + w];
            }
            float m = fmaxf(e0, e1);
            for (int o = 32; o >= 1; o >>= 1) m = fmaxf(m, __shfl_xor(m, o));
            float x0 = __expf(e0 - m), x1 = __expf(e1 - m);
            float ss = x0 + x1;
            for (int o = 32; o >= 1; o >>= 1) ss += __shfl_xor(ss, o);
            esL[bb * 128 + t0] = x0; esL[bb * 128 + t0 + 1] = x1;
            if (lane == 0) riL[bb] = 1.f / ss;
        }
        __syncthreads();

        // ---- phase D: context partials (all 8 waves; b = tid>>8) ----
        {
            int slice = htid >> 6, ig = htid & 63;   // t in [slice*32,+32), i = ig*4..+3
            const char* bsrc = Lm + OFF_BH + b * 32768 + slice * 32 * 256 + ig * 4;
            const float* es = esL + b * 128 + slice * 32;
            float a0 = 0.f, a1 = 0.f, a2 = 0.f, a3 = 0.f;
#pragma unroll
            for (int t = 0; t < 32; t++) {
                float al = es[t];
                uint v = *(const uint*)(bsrc + t * 256);
                a0 += al * (float)(char)(v);
                a1 += al * (float)(char)(v >> 8);
                a2 += al * (float)(char)(v >> 16);
                a3 += al * (float)(char)(v >> 24);
            }
            float* cp = gcC + (b * 4 + slice) * 256 + ig * 4;
            cp[0] = a0; cp[1] = a1; cp[2] = a2; cp[3] = a3;
        }
        __syncthreads();

        // ---- phase E: reduce partials -> Xt ctx half (bf16) ----
        {
            int i = htid;
            float sm = gcC[(b * 4 + 0) * 256 + i] + gcC[(b * 4 + 1) * 256 + i] +
                       gcC[(b * 4 + 2) * 256 + i] + gcC[(b * 4 + 3) * 256 + i];
            Xt[b * 512 + i] = f2bf(sm * riL[b] * (1.f / SH));
        }
        __syncthreads();

        // ---- phase F: ctx-half gate GEMM (ks 0..7 staggered), ub = 2wv,2wv+1 ----
        {
            const u16* xsrc = (lr < 2) ? (Xt + lr * 512) : zb;
            int xstep = (lr < 2) ? 1 : 0;
            f32x4 ac0[4] = {}, ac1[4] = {};
            int ub0 = wv * 2, ub1 = wv * 2 + 1;
#pragma unroll 4
            for (int kk = 0; kk < 8; kk++) {
                int ks = (kk + rot7) & 7;
                short8 af = *(const short8*)(xsrc + (ks * 32 + lq * 8) * xstep);
                const u16* wb0 = Wcat3 + (size_t)((ub0 * 16 + ks) * 4) * 512 + lane * 8;
                const u16* wb1 = Wcat3 + (size_t)((ub1 * 16 + ks) * 4) * 512 + lane * 8;
#pragma unroll
                for (int g = 0; g < 4; g++) {
                    ac0[g] = __builtin_amdgcn_mfma_f32_16x16x32_bf16(
                        af, *(const short8*)(wb0 + g * 512), ac0[g], 0, 0, 0);
                    ac1[g] = __builtin_amdgcn_mfma_f32_16x16x32_bf16(
                        af, *(const short8*)(wb1 + g * 512), ac1[g], 0, 0, 0);
                }
            }
            if (lq == 0) {
#pragma unroll
                for (int g = 0; g < 4; g++) {
                    gcC[(0 * 4 + g) * 256 + ub0 * 16 + lr] = ac0[g][0];
                    gcC[(1 * 4 + g) * 256 + ub0 * 16 + lr] = ac0[g][1];
                    gcC[(0 * 4 + g) * 256 + ub1 * 16 + lr] = ac1[g][0];
                    gcC[(1 * 4 + g) * 256 + ub1 * 16 + lr] = ac1[g][1];
                }
            }
        }
        __syncthreads();

        // ---- phase G: pointwise LSTM (512 threads; b = tid>>8, u = htid) ----
        {
            int u = htid;
            int tgt = tgL[b * 26 + s];
            const float* wt = WohT + (size_t)tgt * 1024;
            float gi = gcC[(b * 4 + 0) * 256 + u] + gcH[(b * 4 + 0) * 256 + u] + bsum[u] + wt[u];
            float gf = gcC[(b * 4 + 1) * 256 + u] + gcH[(b * 4 + 1) * 256 + u] + bsum[256 + u] + wt[256 + u];
            float gg = gcC[(b * 4 + 2) * 256 + u] + gcH[(b * 4 + 2) * 256 + u] + bsum[512 + u] + wt[512 + u];
            float go = gcC[(b * 4 + 3) * 256 + u] + gcH[(b * 4 + 3) * 256 + u] + bsum[768 + u] + wt[768 + u];
            float cn = fast_sig(gf) * creg + fast_sig(gi) * fast_tanh(gg);
            float hn = fast_sig(go) * fast_tanh(cn);
            creg = cn;
            hbf_all[(size_t)s * NB * NH + (size_t)(blk * 2 + b) * 256 + u] = f2bf(hn);
            h8c[b * 256 + u] = (char)q8i(hn, S8);
            Xt[b * 512 + 256 + u] = f2bf(hn);
        }
        __syncthreads();
    }
}

// ---------------- final logits ----------------
__launch_bounds__(256)
__global__ void gen_logits(const u16* __restrict__ hbf_all, const u16* __restrict__ WgenP,
                           const float* __restrict__ b_gen, float* __restrict__ out) {
    __shared__ u16 As[32 * 32];
    __shared__ u16 Bs[128 * 32];
    int mb = blockIdx.x;
    int tid = threadIdx.x;
    int wave = tid >> 6, lane = tid & 63, lr = lane & 15, lq = lane >> 4;
    int wm = wave >> 1, wn = wave & 1;
    f32x4 acc[4] = {};
    for (int kc = 0; kc < 256; kc += 32) {
        __syncthreads();
        {
            int r = tid >> 3, c4 = (tid & 7) * 4;
            *(ushort4*)(As + r * 32 + c4) =
                *(const ushort4*)(hbf_all + (size_t)(mb * 32 + r) * 256 + kc + c4);
        }
        {
            int r = tid >> 1, h16 = (tid & 1) * 16;
            const u16* src = WgenP + (size_t)r * 256 + kc + h16;
            u16* d = Bs + r * 32 + h16;
            *(ushort4*)(d) = *(const ushort4*)(src);
            *(ushort4*)(d + 4) = *(const ushort4*)(src + 4);
            *(ushort4*)(d + 8) = *(const ushort4*)(src + 8);
            *(ushort4*)(d + 12) = *(const ushort4*)(src + 12);
        }
        __syncthreads();
        short8 a = *reinterpret_cast<const short8*>(As + (wm * 16 + lr) * 32 + lq * 8);
        for (int ni = 0; ni < 4; ni++) {
            short8 bb = *reinterpret_cast<const short8*>(Bs + (wn * 64 + ni * 16 + lr) * 32 + lq * 8);
            acc[ni] = __builtin_amdgcn_mfma_f32_16x16x32_bf16(a, bb, acc[ni], 0, 0, 0);
        }
    }
    for (int ni = 0; ni < 4; ni++) {
        int cidx = wn * 64 + ni * 16 + lr;
        if (cidx >= NCLS) continue;
        float bg = b_gen[cidx];
        int mbase = mb * 32 + wm * 16 + lq * 4;
        for (int r = 0; r < 4; r++) {
            int mm = mbase + r;
            int s = mm >> 9;
            int bb_ = mm & 511;
            float v = (cidx == 3) ? -10000.f : (acc[ni][r] + bg);
            out[(size_t)bb_ * (NSTEP * NCLS) + s * NCLS + cidx] = v;
        }
    }
}

extern "C" void kernel_launch(void* const* d_in, const int* in_sizes, int n_in,
                              void* d_out, int out_size, void* d_ws, size_t ws_size,
                              hipStream_t stream) {
    const float* batch_H = (const float*)d_in[0];
    const int* text = (const int*)d_in[1];
    const float* W_i2h = (const float*)d_in[3];
    const float* W_h2h = (const float*)d_in[4];
    const float* b_h2h = (const float*)d_in[5];
    const float* W_score = (const float*)d_in[6];
    const float* W_ih = (const float*)d_in[7];
    const float* W_hh = (const float*)d_in[8];
    const float* b_ih = (const float*)d_in[9];
    const float* b_hh = (const float*)d_in[10];
    const float* W_gen = (const float*)d_in[11];
    const float* b_gen = (const float*)d_in[12];
    float* out = (float*)d_out;

    char* ws = (char*)d_ws;
    size_t off = 0;
    auto alloc = [&](size_t bytes) {
        void* p = ws + off;
        off += (bytes + 255) & ~(size_t)255;
        return p;
    };
    char* projF8 = (char*)alloc((size_t)16777216);    // [b][h][t] int8
    char* bHf8 = (char*)alloc((size_t)16777216);      // [b][t][i] int8
    char* Wh2h_q8 = (char*)alloc(65536);
    u16* Wi2h_bf = (u16*)alloc(65536 * 2);
    u16* Wcat3 = (u16*)alloc((size_t)524288 * 2);     // frag-swizzled LSTM weights
    float* bsum = (float*)alloc(1024 * 4);
    u16* WgenP = (u16*)alloc(32768 * 2);
    float* WohT = (float*)alloc((size_t)102400 * 4);  // [100][1024]
    u16* hbf_all = (u16*)alloc((size_t)NSTEP * NB * NH * 2);

    prep_all<<<256, 256, 0, stream>>>(W_h2h, W_i2h, W_ih, W_hh, b_ih, b_hh, W_gen,
                                      Wh2h_q8, Wi2h_bf, Wcat3, bsum, WgenP, WohT);
    gemm_projH5<<<512, 512, 0, stream>>>(batch_H, Wi2h_bf, projF8, bHf8);
    step_loop7<<<256, 512, 0, stream>>>(projF8, bHf8, Wh2h_q8, b_h2h, W_score,
                                        Wcat3, bsum, WohT, text, hbf_all);
    gen_logits<<<416, 256, 0, stream>>>(hbf_all, WgenP, b_gen, out);
}

// Round 10
// 480.898 us; speedup vs baseline: 3.1888x; 1.1316x over previous
//
#include <hip/hip_runtime.h>
#include <hip/hip_fp16.h>
#include <stdint.h>

typedef unsigned short u16;
typedef unsigned char u8;
typedef unsigned int u32;
typedef __attribute__((ext_vector_type(8))) short short8;
typedef __attribute__((ext_vector_type(4))) float f32x4;
typedef __attribute__((ext_vector_type(4))) int i32x4;

#define NSTEP 26
#define NB 512
#define NT 128
#define NH 256
#define NCLS 100

#define SP 32.0f     // proj_H int8 scale
#define SH 24.0f     // batch_H int8 scale
#define SW 2000.0f   // W_h2h / Wcat int8 scale
#define S8 127.0f    // h int8 scale

#if defined(__has_builtin)
#if __has_builtin(__builtin_amdgcn_sdot4)
#define HAS_SDOT4 1
#endif
#endif

__device__ __forceinline__ u16 f2bf(float f) {
    unsigned u = __float_as_uint(f);
    return (u16)((u + 0x7FFFu + ((u >> 16) & 1u)) >> 16);
}
__device__ __forceinline__ int q8i(float x, float s) {
    float v = fminf(fmaxf(x * s, -127.f), 127.f);
    return __float2int_rn(v);
}
__device__ __forceinline__ float fast_tanh(float x) {
    float e = __expf(2.f * x);
    return 1.f - 2.f / (e + 1.f);
}
__device__ __forceinline__ float fast_sig(float x) { return 1.f / (1.f + __expf(-x)); }
__device__ __forceinline__ void async_g2l(const void* g, void* l) {
    __builtin_amdgcn_global_load_lds((const __attribute__((address_space(1))) u32*)g,
                                     (__attribute__((address_space(3))) u32*)l, 16, 0, 0);
}

// ---------------- prep: ALL weight conversions ----------------
// Wcat8: int8 gate weights in i8-MFMA (16x16x64) B-frag layout:
// idx = (((ub*8 + ks64)*4 + g)*64 + lane)*16 + j ; value = W[g*256+ub*16+(lane&15)]
//                                                        [ks64*64 + (lane>>4)*16 + j]
__global__ void prep_all(const float* __restrict__ W_h2h, const float* __restrict__ W_i2h,
                         const float* __restrict__ W_ih, const float* __restrict__ W_hh,
                         const float* __restrict__ b_ih, const float* __restrict__ b_hh,
                         const float* __restrict__ W_gen,
                         char* __restrict__ Wh2h_q8, u16* __restrict__ Wi2h_bf,
                         char* __restrict__ Wcat8, float* __restrict__ bsum,
                         u16* __restrict__ WgenP, float* __restrict__ WohT) {
    int idx = blockIdx.x * 256 + threadIdx.x;  // 65536 threads
    if (idx < 65536) {
        Wh2h_q8[idx] = (char)q8i(W_h2h[idx], SW);
        Wi2h_bf[idx] = f2bf(W_i2h[idx]);
    }
    for (int i = idx; i < 16 * 8 * 4 * 64 * 16; i += 65536) {
        int j = i & 15, lane = (i >> 4) & 63, g = (i >> 10) & 3, ks64 = (i >> 12) & 7, ub = i >> 15;
        int lr = lane & 15, lq = lane >> 4;
        int rg = g * 256 + ub * 16 + lr;
        int k = ks64 * 64 + lq * 16 + j;
        float v = (k < 256) ? W_ih[(size_t)rg * 356 + k] : W_hh[(size_t)rg * 256 + (k - 256)];
        Wcat8[i] = (char)q8i(v, SW);
    }
    for (int i = idx; i < 100 * 1024; i += 65536) {
        int t = i >> 10, rg = i & 1023;
        WohT[i] = W_ih[(size_t)rg * 356 + 256 + t];
    }
    if (idx < 1024) bsum[idx] = b_ih[idx] + b_hh[idx];
    if (idx < 32768) {
        int r = idx >> 8, ccol = idx & 255;
        WgenP[idx] = (r < NCLS) ? f2bf(W_gen[r * 256 + ccol]) : (u16)0;
    }
}

// ---------------- proj_H GEMM: 1 batch/block, 128x256, 8 waves 2x4 --------
// Writes projF8 [b][h][t] int8 and bHf8 [b][t][i] int8 (direct, no transpose).
__launch_bounds__(512, 3)
__global__ void gemm_projH5(const float* __restrict__ bH, const u16* __restrict__ Wi2h_bf,
                            char* __restrict__ projF8, char* __restrict__ bHf8) {
    __shared__ char gsm[49152];
    u16* As[2] = {(u16*)gsm, (u16*)(gsm + 8192)};
    u16* Bs[2] = {(u16*)(gsm + 16384), (u16*)(gsm + 32768)};
    char* Tt = gsm;   // epilogue: [256 rows][144 pad] int8 (aliases As after final sync)

    int b = blockIdx.x, tid = threadIdx.x;
    int wave = tid >> 6, lane = tid & 63, lr = lane & 15, lq = lane >> 4;
    int wm = wave >> 2, wn = wave & 3;
    int ar = tid >> 2, part = tid & 3;
    const float* asrc = bH + ((size_t)b * 128 + ar) * 256 + part * 8;
    f32x4 acc[4][4] = {};
    uint2 bh[8];

    auto stageB = [&](int kc, int buf) {
        for (int i = 0; i < 2; i++) {
            int ch = wave * 2 + i;
            int row = ch * 16 + (lane >> 2);
            const u16* g = Wi2h_bf + (size_t)row * 256 + kc * 32 + (lane & 3) * 8;
            async_g2l(g, (char*)Bs[buf] + ch * 1024 + lane * 16);
        }
    };
    auto writeA = [&](int kc, int buf, float4 v0, float4 v1) {
        u16* dst = As[buf] + ar * 32 + part * 8;
        dst[0] = f2bf(v0.x); dst[1] = f2bf(v0.y); dst[2] = f2bf(v0.z); dst[3] = f2bf(v0.w);
        dst[4] = f2bf(v1.x); dst[5] = f2bf(v1.y); dst[6] = f2bf(v1.z); dst[7] = f2bf(v1.w);
        uint p0 = (uint)(u8)q8i(v0.x, SH) | ((uint)(u8)q8i(v0.y, SH) << 8) |
                  ((uint)(u8)q8i(v0.z, SH) << 16) | ((uint)(u8)q8i(v0.w, SH) << 24);
        uint p1 = (uint)(u8)q8i(v1.x, SH) | ((uint)(u8)q8i(v1.y, SH) << 8) |
                  ((uint)(u8)q8i(v1.z, SH) << 16) | ((uint)(u8)q8i(v1.w, SH) << 24);
        bh[kc].x = p0; bh[kc].y = p1;
    };

    float4 a0 = *(const float4*)(asrc);
    float4 a1 = *(const float4*)(asrc + 4);
    stageB(0, 0);
    writeA(0, 0, a0, a1);
    __syncthreads();

    for (int kc = 0; kc < 8; kc++) {
        int cur = kc & 1, nxt = cur ^ 1;
        if (kc < 7) {
            stageB(kc + 1, nxt);
            a0 = *(const float4*)(asrc + (kc + 1) * 32);
            a1 = *(const float4*)(asrc + (kc + 1) * 32 + 4);
        }
        short8 af[4];
        for (int mi = 0; mi < 4; mi++)
            af[mi] = *(const short8*)(As[cur] + (wm * 64 + mi * 16 + lr) * 32 + lq * 8);
        for (int ni = 0; ni < 4; ni++) {
            short8 bf = *(const short8*)(Bs[cur] + (wn * 64 + ni * 16 + lr) * 32 + lq * 8);
            for (int mi = 0; mi < 4; mi++)
                acc[mi][ni] = __builtin_amdgcn_mfma_f32_16x16x32_bf16(af[mi], bf, acc[mi][ni], 0, 0, 0);
        }
        if (kc < 7) writeA(kc + 1, nxt, a0, a1);
        __syncthreads();
    }

    // bHf8 [b][t][i]: straight from the A-quant registers, coalesced uint2 stores.
    for (int kc = 0; kc < 8; kc++)
        *(uint2*)(bHf8 + (size_t)b * 32768 + ar * 256 + kc * 32 + part * 8) = bh[kc];

    // projF8 transpose epilogue (int8 [b][h][t])
    for (int mi = 0; mi < 4; mi++)
        for (int ni = 0; ni < 4; ni++) {
            int h = wn * 64 + ni * 16 + lr;
            int t = wm * 64 + mi * 16 + lq * 4;
            f32x4 v = acc[mi][ni];
            uint pk = (uint)(u8)q8i(v[0], SP) | ((uint)(u8)q8i(v[1], SP) << 8) |
                      ((uint)(u8)q8i(v[2], SP) << 16) | ((uint)(u8)q8i(v[3], SP) << 24);
            *(uint*)(Tt + h * 144 + t) = pk;
        }
    __syncthreads();
    {
        int hrow = tid >> 1, half = tid & 1;
        const char* src = Tt + hrow * 144 + half * 64;
        char* dst = projF8 + (size_t)b * 32768 + hrow * 128 + half * 64;
        uint4 v0 = *(const uint4*)(src);
        uint4 v1 = *(const uint4*)(src + 16);
        uint4 v2 = *(const uint4*)(src + 32);
        uint4 v3 = *(const uint4*)(src + 48);
        *(uint4*)(dst) = v0; *(uint4*)(dst + 16) = v1;
        *(uint4*)(dst + 32) = v2; *(uint4*)(dst + 48) = v3;
    }
}

// ---------------- persistent block-local step loop: 256 blocks x 512 threads ----------
// R9 structure (overlapped h-burst + stagger) with the gate GEMM in INT8
// (v_mfma_i32_16x16x64_i8): weight stream halves (1MB -> 512KB/step/CU), MFMA count
// halves. h-half A-operand = existing h8c (scale 127); ctx-half A-operand = Xq8 =
// round(sm*rinv) which is EXACTLY ctx*24 in the bHf8 scale (convex combo of int8,
// bounded +-127). i32 accumulation is exact; scales 1/(SW*S8), 1/(SW*SH) applied at
// gcH/gcC write. Diagnosed L2 broadcast floor (7.4us/step bf16) halves to 3.7.
#define OFF_PROJ 0          // [2][256][128] int8, t-chunk XOR swizzled
#define OFF_BH   65536      // [2][128][256] int8, t-major
#define OFF_XQ   131072     // char [2][256] ctx*24 int8
#define OFF_ZB   131584     // 64B zero block
#define OFF_PH   131648     // f32 [2][256]
#define OFF_GC   133696     // f32 [2][4][256]  ctx partials | ctx-gates (aliased)
#define OFF_GH   141888     // f32 [2][4][256]  h-gates (written by burst)
#define OFF_EP   150080     // f32 [2][128*4]   e partials
#define OFF_ES   154176     // f32 [2][128]     exp(e-m)
#define OFF_H8   155200     // char [2][256]
#define OFF_WS   155712     // f32 [256] W_score
#define OFF_B2   156736     // f32 [256] b_h2h
#define OFF_TG   157760     // int [2][26]
#define OFF_RI   158016     // f32 [2]
#define LDS_TOT  158080

__launch_bounds__(512, 1)
__global__ void step_loop8(const char* __restrict__ projF8, const char* __restrict__ bHf8,
                           const char* __restrict__ Wh2h_q8, const float* __restrict__ b_h2h,
                           const float* __restrict__ W_score, const char* __restrict__ Wcat8,
                           const float* __restrict__ bsum, const float* __restrict__ WohT,
                           const int* __restrict__ text, u16* __restrict__ hbf_all) {
    __shared__ __align__(16) char Lm[LDS_TOT];
    char* Xq8 = Lm + OFF_XQ;
    char* zbc = Lm + OFF_ZB;
    float* phL = (float*)(Lm + OFF_PH);
    float* gcC = (float*)(Lm + OFF_GC);
    float* gcH = (float*)(Lm + OFF_GH);
    float* epL = (float*)(Lm + OFF_EP);
    float* esL = (float*)(Lm + OFF_ES);
    char* h8c = Lm + OFF_H8;
    float* wsL = (float*)(Lm + OFF_WS);
    float* b2L = (float*)(Lm + OFF_B2);
    int* tgL = (int*)(Lm + OFF_TG);
    float* riL = (float*)(Lm + OFF_RI);

    int blk = blockIdx.x, tid = threadIdx.x;
    int lane = tid & 63;
    int wv = tid >> 6;                       // wave 0..7
    int lr = lane & 15, lq = lane >> 4;
    int rot = (blk >> 3) & 15;               // sweep stagger (same-XCD blocks differ)
    // attn decomposition (waves 0-3, tid<256): unit u = tid, both batches
    int tq = tid & 7, hg = (tid & 255) >> 3; // e-phase: t-chunk, h-group in [0,32)
    // D/E/G decomposition (512 threads): b = tid>>8, htid = tid&255
    int b = tid >> 8, htid = tid & 255;

    // ---- prologue: stage projF8 (swizzled) + bHf8 into LDS, init state ----
    {
        const uint4* pg = (const uint4*)(projF8 + (size_t)blk * 65536);
        const uint4* bg = (const uint4*)(bHf8 + (size_t)blk * 65536);
#pragma unroll
        for (int q = 0; q < 8; q++) {
            int w = tid + q * 512;           // uint4 index in [0,4096)
            int c = w & 7;                   // t-chunk
            int R = (w >> 3) & 255;          // h row
            int b2 = w >> 11;                // batch 0/1
            uint4 v = pg[w];
            *(uint4*)(Lm + OFF_PROJ + b2 * 32768 + R * 128 + (((c ^ (R >> 3)) & 7) << 4)) = v;
            *(uint4*)(Lm + OFF_BH + w * 16) = bg[w];
        }
        if (tid < 128) *(uint*)(h8c + tid * 4) = 0;   // zero h8 for s=0 burst
        if (tid < 16) *(uint*)(zbc + tid * 4) = 0;
        if (tid < 256) { wsL[tid] = W_score[tid]; b2L[tid] = b_h2h[tid]; }
        if (tid < 52) {
            int bb = tid >= 26, st = tid - bb * 26;
            tgL[bb * 26 + st] = text[(blk * 2 + bb) * NSTEP + st];
        }
    }
    __syncthreads();

    float creg = 0.f;    // c state for (b = tid>>8, u = tid&255)

    for (int s = 0; s < NSTEP; s++) {
        // ================= region 1: attn A+B (waves 0-3) || h-burst (waves 4-7) ======
        if (wv < 4) {
            // ---- phase A: ph for both batches (unit u = tid) ----
            {
                int u = tid;
                float v0, v1;
                if (s == 0) {
                    v0 = v1 = b2L[u];
                } else {
                    const uint4* wrow = (const uint4*)(Wh2h_q8 + (size_t)u * 256);
                    const uint4* hv0 = (const uint4*)(h8c);
                    const uint4* hv1 = (const uint4*)(h8c + 256);
                    int a0 = 0, a1 = 0;
#pragma unroll
                    for (int k = 0; k < 16; k++) {
                        uint4 w = wrow[k];
                        uint4 ha = hv0[k];
                        uint4 hb = hv1[k];
#ifdef HAS_SDOT4
                        a0 = __builtin_amdgcn_sdot4((int)w.x, (int)ha.x, a0, false);
                        a0 = __builtin_amdgcn_sdot4((int)w.y, (int)ha.y, a0, false);
                        a0 = __builtin_amdgcn_sdot4((int)w.z, (int)ha.z, a0, false);
                        a0 = __builtin_amdgcn_sdot4((int)w.w, (int)ha.w, a0, false);
                        a1 = __builtin_amdgcn_sdot4((int)w.x, (int)hb.x, a1, false);
                        a1 = __builtin_amdgcn_sdot4((int)w.y, (int)hb.y, a1, false);
                        a1 = __builtin_amdgcn_sdot4((int)w.z, (int)hb.z, a1, false);
                        a1 = __builtin_amdgcn_sdot4((int)w.w, (int)hb.w, a1, false);
#else
                        uint wv_[4] = {w.x, w.y, w.z, w.w};
                        uint ha_[4] = {ha.x, ha.y, ha.z, ha.w};
                        uint hb_[4] = {hb.x, hb.y, hb.z, hb.w};
                        for (int c = 0; c < 4; c++)
                            for (int by = 0; by < 32; by += 8) {
                                a0 += (int)(char)(wv_[c] >> by) * (int)(char)(ha_[c] >> by);
                                a1 += (int)(char)(wv_[c] >> by) * (int)(char)(hb_[c] >> by);
                            }
#endif
                    }
                    v0 = (float)a0 * (1.f / (SW * S8)) + b2L[u];
                    v1 = (float)a1 * (1.f / (SW * S8)) + b2L[u];
                }
                phL[u] = v0;
                phL[256 + u] = v1;
            }
            // A->B communication is within each wave's 8-lane cluster: fence, no barrier
            asm volatile("s_waitcnt lgkmcnt(0)" ::: "memory");
            // ---- phase B: e-loop for both batches (LDS proj, swizzled) ----
            {
                const __half2 c3 = __float2half2_rn(-0.0016249f), c2 = __float2half2_rn(0.031520f);
                const __half2 c1h = __float2half2_rn(-0.222110f), c0h = __float2half2_rn(0.962117f);
                const float inv = 1.f / SP;
                int t0e = tq * 16;
                int co = ((tq ^ hg) & 7) << 4;   // swizzled chunk offset (R>>3 == hg)
                for (int bb = 0; bb < 2; bb++) {
                    __half2 acc2[8];
#pragma unroll
                    for (int q = 0; q < 8; q++) acc2[q] = __float2half2_rn(0.f);
                    const char* baseL = Lm + OFF_PROJ + bb * 32768 + co;
#pragma unroll
                    for (int hh = 0; hh < 8; hh++) {
                        int R = hg * 8 + hh;
                        uint4 uu = *(const uint4*)(baseL + R * 128);
                        float phv = phL[bb * 256 + R];
                        __half2 wv2 = __float2half2_rn(wsL[R]);
                        uint wq[4] = {uu.x, uu.y, uu.z, uu.w};
#pragma unroll
                        for (int wi = 0; wi < 4; wi++) {
                            uint w = wq[wi];
#pragma unroll
                            for (int pp = 0; pp < 2; pp++) {
                                float xa = fmaf((float)(char)(w >> (pp * 16)), inv, phv);
                                float xb = fmaf((float)(char)(w >> (pp * 16 + 8)), inv, phv);
                                xa = fminf(fmaxf(xa, -3.0f), 3.0f);
                                xb = fminf(fmaxf(xb, -3.0f), 3.0f);
                                __half2 x = __floats2half2_rn(xa, xb);
                                __half2 u2 = __hmul2(x, x);
                                __half2 p = __hfma2(__hfma2(__hfma2(c3, u2, c2), u2, c1h), u2, c0h);
                                acc2[wi * 2 + pp] = __hfma2(__hmul2(x, p), wv2, acc2[wi * 2 + pp]);
                            }
                        }
                    }
                    float a16[16];
#pragma unroll
                    for (int q = 0; q < 8; q++) {
                        a16[q * 2] = __low2float(acc2[q]);
                        a16[q * 2 + 1] = __high2float(acc2[q]);
                    }
#pragma unroll
                    for (int j = 0; j < 16; j++) {
                        float v = a16[j];
                        v += __shfl_xor(v, 8);
                        v += __shfl_xor(v, 16);
                        v += __shfl_xor(v, 32);
                        a16[j] = v;
                    }
                    if (lane < 8) {
                        int t0w = lane * 16;
#pragma unroll
                        for (int j = 0; j < 16; j++) epL[bb * 512 + (t0w + j) * 4 + wv] = a16[j];
                    }
                }
            }
        } else {
            // ---- h-burst (int8): all 16 ub, ks64 4..7, staggered sweep per block ----
            int w4 = wv - 4;
            const char* xsH = (lr < 2) ? (h8c + lr * 256) : zbc;
            int xstep = (lr < 2) ? 1 : 0;
#pragma unroll
            for (int r = 0; r < 4; r++) {
                int ub = (w4 * 4 + r + rot) & 15;
                i32x4 ac[4] = {};
#pragma unroll
                for (int kk = 0; kk < 4; kk++) {
                    int ks = (kk + rot) & 3;     // h-half ks64 = 4 + ks
                    i32x4 av = *(const i32x4*)(xsH + (ks * 64 + lq * 16) * xstep);
                    const char* wb = Wcat8 + (size_t)((ub * 8 + 4 + ks) * 4) * 1024 + lane * 16;
#pragma unroll
                    for (int g = 0; g < 4; g++)
                        ac[g] = __builtin_amdgcn_mfma_i32_16x16x64_i8(
                            av, *(const i32x4*)(wb + g * 1024), ac[g], 0, 0, 0);
                }
                if (lq == 0) {
#pragma unroll
                    for (int g = 0; g < 4; g++) {
                        gcH[(0 * 4 + g) * 256 + ub * 16 + lr] = (float)ac[g][0] * (1.f / (SW * S8));
                        gcH[(1 * 4 + g) * 256 + ub * 16 + lr] = (float)ac[g][1] * (1.f / (SW * S8));
                    }
                }
            }
        }
        __syncthreads();

        // ---- phase C: softmax (waves 0,1: one batch each) ----
        if (wv < 2) {
            int bb = wv;
            int t0 = lane * 2;
            float e0 = 0.f, e1 = 0.f;
#pragma unroll
            for (int w = 0; w < 4; w++) {
                e0 += epL[bb * 512 + t0 * 4 + w];
                e1 += epL[bb * 512 + (t0 + 1) * 4 + w];
            }
            float m = fmaxf(e0, e1);
            for (int o = 32; o >= 1; o >>= 1) m = fmaxf(m, __shfl_xor(m, o));
            float x0 = __expf(e0 - m), x1 = __expf(e1 - m);
            float ss = x0 + x1;
            for (int o = 32; o >= 1; o >>= 1) ss += __shfl_xor(ss, o);
            esL[bb * 128 + t0] = x0; esL[bb * 128 + t0 + 1] = x1;
            if (lane == 0) riL[bb] = 1.f / ss;
        }
        __syncthreads();

        // ---- phase D: context partials (all 8 waves; b = tid>>8) ----
        {
            int slice = htid >> 6, ig = htid & 63;   // t in [slice*32,+32), i = ig*4..+3
            const char* bsrc = Lm + OFF_BH + b * 32768 + slice * 32 * 256 + ig * 4;
            const float* es = esL + b * 128 + slice * 32;
            float a0 = 0.f, a1 = 0.f, a2 = 0.f, a3 = 0.f;
#pragma unroll
            for (int t = 0; t < 32; t++) {
                float al = es[t];
                uint v = *(const uint*)(bsrc + t * 256);
                a0 += al * (float)(char)(v);
                a1 += al * (float)(char)(v >> 8);
                a2 += al * (float)(char)(v >> 16);
                a3 += al * (float)(char)(v >> 24);
            }
            float* cp = gcC + (b * 4 + slice) * 256 + ig * 4;
            cp[0] = a0; cp[1] = a1; cp[2] = a2; cp[3] = a3;
        }
        __syncthreads();

        // ---- phase E: reduce partials -> Xq8 ctx (int8; sm*rinv == ctx*24 exactly) ----
        {
            int i = htid;
            float sm = gcC[(b * 4 + 0) * 256 + i] + gcC[(b * 4 + 1) * 256 + i] +
                       gcC[(b * 4 + 2) * 256 + i] + gcC[(b * 4 + 3) * 256 + i];
            Xq8[b * 256 + i] = (char)q8i(sm * riL[b], 1.f);
        }
        __syncthreads();

        // ---- phase F: ctx-half gate GEMM int8 (ks64 0..3 staggered), ub = 2wv,2wv+1 ----
        {
            const char* xsC = (lr < 2) ? (Xq8 + lr * 256) : zbc;
            int xstep = (lr < 2) ? 1 : 0;
            i32x4 ac0[4] = {}, ac1[4] = {};
            int ub0 = wv * 2, ub1 = wv * 2 + 1;
#pragma unroll
            for (int kk = 0; kk < 4; kk++) {
                int ks = (kk + rot) & 3;
                i32x4 av = *(const i32x4*)(xsC + (ks * 64 + lq * 16) * xstep);
                const char* wb0 = Wcat8 + (size_t)((ub0 * 8 + ks) * 4) * 1024 + lane * 16;
                const char* wb1 = Wcat8 + (size_t)((ub1 * 8 + ks) * 4) * 1024 + lane * 16;
#pragma unroll
                for (int g = 0; g < 4; g++) {
                    ac0[g] = __builtin_amdgcn_mfma_i32_16x16x64_i8(
                        av, *(const i32x4*)(wb0 + g * 1024), ac0[g], 0, 0, 0);
                    ac1[g] = __builtin_amdgcn_mfma_i32_16x16x64_i8(
                        av, *(const i32x4*)(wb1 + g * 1024), ac1[g], 0, 0, 0);
                }
            }
            if (lq == 0) {
#pragma unroll
                for (int g = 0; g < 4; g++) {
                    gcC[(0 * 4 + g) * 256 + ub0 * 16 + lr] = (float)ac0[g][0] * (1.f / (SW * SH));
                    gcC[(1 * 4 + g) * 256 + ub0 * 16 + lr] = (float)ac0[g][1] * (1.f / (SW * SH));
                    gcC[(0 * 4 + g) * 256 + ub1 * 16 + lr] = (float)ac1[g][0] * (1.f / (SW * SH));
                    gcC[(1 * 4 + g) * 256 + ub1 * 16 + lr] = (float)ac1[g][1] * (1.f / (SW * SH));
                }
            }
        }
        __syncthreads();

        // ---- phase G: pointwise LSTM (512 threads; b = tid>>8, u = htid) ----
        {
            int u = htid;
            int tgt = tgL[b * 26 + s];
            const float* wt = WohT + (size_t)tgt * 1024;
            float gi = gcC[(b * 4 + 0) * 256 + u] + gcH[(b * 4 + 0) * 256 + u] + bsum[u] + wt[u];
            float gf = gcC[(b * 4 + 1) * 256 + u] + gcH[(b * 4 + 1) * 256 + u] + bsum[256 + u] + wt[256 + u];
            float gg = gcC[(b * 4 + 2) * 256 + u] + gcH[(b * 4 + 2) * 256 + u] + bsum[512 + u] + wt[512 + u];
            float go = gcC[(b * 4 + 3) * 256 + u] + gcH[(b * 4 + 3) * 256 + u] + bsum[768 + u] + wt[768 + u];
            float cn = fast_sig(gf) * creg + fast_sig(gi) * fast_tanh(gg);
            float hn = fast_sig(go) * fast_tanh(cn);
            creg = cn;
            hbf_all[(size_t)s * NB * NH + (size_t)(blk * 2 + b) * 256 + u] = f2bf(hn);
            h8c[b * 256 + u] = (char)q8i(hn, S8);
        }
        __syncthreads();
    }
}

// ---------------- final logits ----------------
__launch_bounds__(256)
__global__ void gen_logits(const u16* __restrict__ hbf_all, const u16* __restrict__ WgenP,
                           const float* __restrict__ b_gen, float* __restrict__ out) {
    __shared__ u16 As[32 * 32];
    __shared__ u16 Bs[128 * 32];
    int mb = blockIdx.x;
    int tid = threadIdx.x;
    int wave = tid >> 6, lane = tid & 63, lr = lane & 15, lq = lane >> 4;
    int wm = wave >> 1, wn = wave & 1;
    f32x4 acc[4] = {};
    for (int kc = 0; kc < 256; kc += 32) {
        __syncthreads();
        {
            int r = tid >> 3, c4 = (tid & 7) * 4;
            *(ushort4*)(As + r * 32 + c4) =
                *(const ushort4*)(hbf_all + (size_t)(mb * 32 + r) * 256 + kc + c4);
        }
        {
            int r = tid >> 1, h16 = (tid & 1) * 16;
            const u16* src = WgenP + (size_t)r * 256 + kc + h16;
            u16* d = Bs + r * 32 + h16;
            *(ushort4*)(d) = *(const ushort4*)(src);
            *(ushort4*)(d + 4) = *(const ushort4*)(src + 4);
            *(ushort4*)(d + 8) = *(const ushort4*)(src + 8);
            *(ushort4*)(d + 12) = *(const ushort4*)(src + 12);
        }
        __syncthreads();
        short8 a = *reinterpret_cast<const short8*>(As + (wm * 16 + lr) * 32 + lq * 8);
        for (int ni = 0; ni < 4; ni++) {
            short8 bb = *reinterpret_cast<const short8*>(Bs + (wn * 64 + ni * 16 + lr) * 32 + lq * 8);
            acc[ni] = __builtin_amdgcn_mfma_f32_16x16x32_bf16(a, bb, acc[ni], 0, 0, 0);
        }
    }
    for (int ni = 0; ni < 4; ni++) {
        int cidx = wn * 64 + ni * 16 + lr;
        if (cidx >= NCLS) continue;
        float bg = b_gen[cidx];
        int mbase = mb * 32 + wm * 16 + lq * 4;
        for (int r = 0; r < 4; r++) {
            int mm = mbase + r;
            int s = mm >> 9;
            int bb_ = mm & 511;
            float v = (cidx == 3) ? -10000.f : (acc[ni][r] + bg);
            out[(size_t)bb_ * (NSTEP * NCLS) + s * NCLS + cidx] = v;
        }
    }
}

extern "C" void kernel_launch(void* const* d_in, const int* in_sizes, int n_in,
                              void* d_out, int out_size, void* d_ws, size_t ws_size,
                              hipStream_t stream) {
    const float* batch_H = (const float*)d_in[0];
    const int* text = (const int*)d_in[1];
    const float* W_i2h = (const float*)d_in[3];
    const float* W_h2h = (const float*)d_in[4];
    const float* b_h2h = (const float*)d_in[5];
    const float* W_score = (const float*)d_in[6];
    const float* W_ih = (const float*)d_in[7];
    const float* W_hh = (const float*)d_in[8];
    const float* b_ih = (const float*)d_in[9];
    const float* b_hh = (const float*)d_in[10];
    const float* W_gen = (const float*)d_in[11];
    const float* b_gen = (const float*)d_in[12];
    float* out = (float*)d_out;

    char* ws = (char*)d_ws;
    size_t off = 0;
    auto alloc = [&](size_t bytes) {
        void* p = ws + off;
        off += (bytes + 255) & ~(size_t)255;
        return p;
    };
    char* projF8 = (char*)alloc((size_t)16777216);    // [b][h][t] int8
    char* bHf8 = (char*)alloc((size_t)16777216);      // [b][t][i] int8
    char* Wh2h_q8 = (char*)alloc(65536);
    u16* Wi2h_bf = (u16*)alloc(65536 * 2);
    char* Wcat8 = (char*)alloc((size_t)524288);       // int8 gate weights, i8-frag layout
    float* bsum = (float*)alloc(1024 * 4);
    u16* WgenP = (u16*)alloc(32768 * 2);
    float* WohT = (float*)alloc((size_t)102400 * 4);  // [100][1024]
    u16* hbf_all = (u16*)alloc((size_t)NSTEP * NB * NH * 2);

    prep_all<<<256, 256, 0, stream>>>(W_h2h, W_i2h, W_ih, W_hh, b_ih, b_hh, W_gen,
                                      Wh2h_q8, Wi2h_bf, Wcat8, bsum, WgenP, WohT);
    gemm_projH5<<<512, 512, 0, stream>>>(batch_H, Wi2h_bf, projF8, bHf8);
    step_loop8<<<256, 512, 0, stream>>>(projF8, bHf8, Wh2h_q8, b_h2h, W_score,
                                        Wcat8, bsum, WohT, text, hbf_all);
    gen_logits<<<416, 256, 0, stream>>>(hbf_all, WgenP, b_gen, out);
}